// Round 7
// baseline (626.750 us; speedup 1.0000x reference)
//
#include <hip/hip_runtime.h>
#include <hip/hip_bf16.h>
#include <math.h>

#define N_NODES 50000
#define N_EDGES 800000
#define IN_F    128
#define HID     128
#define CLS     32
#define NHEAD   4
#define NBUCK   196        // ceil(N_NODES / 256)

typedef __attribute__((ext_vector_type(8))) short  short8;
typedef __attribute__((ext_vector_type(4))) float  floatx4;

// ---------- f32 -> bf16 (RNE) ----------
static __device__ __forceinline__ unsigned short f2bf(float f) {
    unsigned int u = __float_as_uint(f);
    return (unsigned short)((u + 0x7fffu + ((u >> 16) & 1u)) >> 16);
}
static __device__ __forceinline__ float2 bf2f2(unsigned int u) {
    return make_float2(__uint_as_float(u << 16), __uint_as_float(u & 0xffff0000u));
}
static __device__ __forceinline__ float elu1(float x) {
    return x > 0.f ? x : expm1f(x);
}

// ---------- weight conversion: 3 matrices per launch ----------
__global__ __launch_bounds__(256) void conv3(
    const float* __restrict__ a0, const float* __restrict__ a1, const float* __restrict__ a2,
    unsigned short* __restrict__ o0, unsigned short* __restrict__ o1, unsigned short* __restrict__ o2,
    int count)
{
    const float* in; unsigned short* out;
    if (blockIdx.y == 0) { in = a0; out = o0; }
    else if (blockIdx.y == 1) { in = a1; out = o1; }
    else { in = a2; out = o2; }
    int i = blockIdx.x * 256 + threadIdx.x;
    if (i < count) out[i] = f2bf(in[i]);
}

// ================= CSR build: 2-pass coarse-bucket counting sort =================
__global__ __launch_bounds__(256) void bucket_hist(
    const int* __restrict__ e0, const int* __restrict__ e1,
    const int* __restrict__ e2, const int* __restrict__ e3,
    int* __restrict__ bcnt, int nE)
{
    const int s = blockIdx.y;
    const int* ep = (s == 0) ? e0 : (s == 1) ? e1 : (s == 2) ? e2 : e3;
    __shared__ int h[NBUCK];
    for (int i = threadIdx.x; i < NBUCK; i += 256) h[i] = 0;
    __syncthreads();
    for (int e = blockIdx.x * 256 + threadIdx.x; e < nE; e += gridDim.x * 256)
        atomicAdd(&h[ep[e] >> 8], 1);
    __syncthreads();
    for (int i = threadIdx.x; i < NBUCK; i += 256)
        if (h[i]) atomicAdd(&bcnt[s * NBUCK + i], h[i]);
}

__global__ __launch_bounds__(256) void bucket_scan(
    const int* __restrict__ bcnt, int* __restrict__ bbase, int* __restrict__ bcur)
{
    int s = blockIdx.x;
    __shared__ int tmp[256];
    int v = (threadIdx.x < NBUCK) ? bcnt[s * NBUCK + threadIdx.x] : 0;
    tmp[threadIdx.x] = v; __syncthreads();
    for (int o = 1; o < 256; o <<= 1) {
        int t = (threadIdx.x >= o) ? tmp[threadIdx.x - o] : 0;
        __syncthreads(); tmp[threadIdx.x] += t; __syncthreads();
    }
    int excl = tmp[threadIdx.x] - v;
    if (threadIdx.x < NBUCK) {
        bbase[s * (NBUCK + 1) + threadIdx.x] = excl;
        bcur[s * NBUCK + threadIdx.x] = excl;
    }
    if (threadIdx.x == NBUCK - 1)
        bbase[s * (NBUCK + 1) + NBUCK] = excl + v;
}

#define TILE 8192
__global__ __launch_bounds__(256) void pass1_scatter(
    const int* __restrict__ e0, const int* __restrict__ e1,
    const int* __restrict__ e2, const int* __restrict__ e3,
    int* __restrict__ bcur, int2* __restrict__ pairs, int nE)
{
    const int s = blockIdx.y;
    const int* ep = (s == 0) ? e0 : (s == 1) ? e1 : (s == 2) ? e2 : e3;
    const int tile0 = blockIdx.x * TILE;
    __shared__ int hist[NBUCK], base[NBUCK], cur[NBUCK];
    for (int i = threadIdx.x; i < NBUCK; i += 256) { hist[i] = 0; cur[i] = 0; }
    __syncthreads();
    for (int i = threadIdx.x; i < TILE; i += 256) {
        int e = tile0 + i;
        if (e < nE) atomicAdd(&hist[ep[e] >> 8], 1);
    }
    __syncthreads();
    for (int i = threadIdx.x; i < NBUCK; i += 256)
        base[i] = hist[i] ? atomicAdd(&bcur[s * NBUCK + i], hist[i]) : 0;
    __syncthreads();
    int2* pp = pairs + (size_t)s * nE;
    for (int i = threadIdx.x; i < TILE; i += 256) {
        int e = tile0 + i;
        if (e < nE) {
            int src = ep[e], dst = ep[e + nE];
            int b = src >> 8;
            int r = atomicAdd(&cur[b], 1);
            pp[base[b] + r] = make_int2(src, dst);
        }
    }
}

__global__ __launch_bounds__(256) void pass2_place(
    const int2* __restrict__ pairs, const int* __restrict__ bbase,
    int* __restrict__ rowptr, int* __restrict__ deg, int* __restrict__ col,
    int nE, int n)
{
    const int s = blockIdx.y, b = blockIdx.x;
    const int base0 = bbase[s * (NBUCK + 1) + b];
    const int ecnt  = bbase[s * (NBUCK + 1) + b + 1] - base0;
    const int2* pp = pairs + (size_t)s * nE + base0;
    __shared__ int hist[256], cur[256];
    hist[threadIdx.x] = 0;
    __syncthreads();
    for (int i = threadIdx.x; i < ecnt; i += 256)
        atomicAdd(&hist[pp[i].x & 255], 1);
    __syncthreads();
    int v = hist[threadIdx.x];
    cur[threadIdx.x] = v; __syncthreads();
    for (int o = 1; o < 256; o <<= 1) {
        int t = (threadIdx.x >= o) ? cur[threadIdx.x - o] : 0;
        __syncthreads(); cur[threadIdx.x] += t; __syncthreads();
    }
    int excl = cur[threadIdx.x] - v;
    int node = b * 256 + threadIdx.x;
    if (node < n) {
        rowptr[(size_t)s * n + node] = base0 + excl;
        deg[(size_t)s * n + node] = v;
    }
    __syncthreads();
    cur[threadIdx.x] = excl;
    __syncthreads();
    int* colp = col + (size_t)s * nE + base0;
    for (int i = threadIdx.x; i < ecnt; i += 256) {
        int2 pr = pp[i];
        int r = atomicAdd(&cur[pr.x & 255], 1);
        colp[r] = pr.y;
    }
}

// ================= MFMA Q/K/V projection =================
// q: node-major f32 [node][A].  k/v: HEAD-MAJOR bf16 [head][node][DK].
template<bool ELUIN>
static __device__ __forceinline__ short8 pack8t(const float* p) {
    float4 a = *(const float4*)p;
    float4 b = *(const float4*)(p + 4);
    if constexpr (ELUIN) {
        a.x = elu1(a.x); a.y = elu1(a.y); a.z = elu1(a.z); a.w = elu1(a.w);
        b.x = elu1(b.x); b.y = elu1(b.y); b.z = elu1(b.z); b.w = elu1(b.w);
    }
    short8 v;
    v[0] = (short)f2bf(a.x); v[1] = (short)f2bf(a.y);
    v[2] = (short)f2bf(a.z); v[3] = (short)f2bf(a.w);
    v[4] = (short)f2bf(b.x); v[5] = (short)f2bf(b.y);
    v[6] = (short)f2bf(b.z); v[7] = (short)f2bf(b.w);
    return v;
}

template<int NT, int A, int DK, bool BF>
__device__ __forceinline__ void mat_mfma(
    const short8* xf, const unsigned short* W, const float* b,
    void* o, int node0, int r, int kg, int n)
{
    floatx4 acc[NT];
#pragma unroll
    for (int nt = 0; nt < NT; ++nt) {
        float bb = b[nt * 16 + r];
        acc[nt] = (floatx4){bb, bb, bb, bb};
    }
#pragma unroll
    for (int ks = 0; ks < 4; ++ks) {
#pragma unroll
        for (int nt = 0; nt < NT; ++nt) {
            short8 wf = *(const short8*)((const short*)W + (size_t)(nt * 16 + r) * IN_F + ks * 32 + kg * 8);
            acc[nt] = __builtin_amdgcn_mfma_f32_16x16x32_bf16(xf[ks], wf, acc[nt], 0, 0, 0);
        }
    }
#pragma unroll
    for (int nt = 0; nt < NT; ++nt) {
        int oc = nt * 16 + r;
#pragma unroll
        for (int reg = 0; reg < 4; ++reg) {
            int node = node0 + kg * 4 + reg;
            if constexpr (BF) {
                size_t idx = (size_t)(oc / DK) * ((size_t)n * DK) + (size_t)node * DK + (oc % DK);
                ((unsigned short*)o)[idx] = f2bf(acc[nt][reg]);
            } else {
                ((float*)o)[(size_t)node * A + oc] = acc[nt][reg];
            }
        }
    }
}

template<int A, int DK, bool ELUIN>
__global__ __launch_bounds__(256) void qkv_mfma(
    const float* __restrict__ x,
    const unsigned short* __restrict__ Wqb, const float* __restrict__ bq,
    const unsigned short* __restrict__ Wkb, const float* __restrict__ bk,
    const unsigned short* __restrict__ Wvb, const float* __restrict__ bv,
    float* __restrict__ qo, unsigned short* __restrict__ ko, unsigned short* __restrict__ vo,
    int n)
{
    constexpr int NT = A / 16;
    const int wave = threadIdx.x >> 6;
    const int lane = threadIdx.x & 63;
    const int node0 = blockIdx.x * 64 + wave * 16;
    if (node0 >= n) return;
    const int r  = lane & 15;
    const int kg = lane >> 4;

    short8 xf[4];
    const float* xr = x + (size_t)(node0 + r) * IN_F + kg * 8;
#pragma unroll
    for (int ks = 0; ks < 4; ++ks) xf[ks] = pack8t<ELUIN>(xr + ks * 32);

    mat_mfma<NT, A, DK, false>(xf, Wqb, bq, qo, node0, r, kg, n);
    mat_mfma<NT, A, DK, true >(xf, Wkb, bk, ko, node0, r, kg, n);
    mat_mfma<NT, A, DK, true >(xf, Wvb, bv, vo, node0, r, kg, n);
}

// ================= layer-0 two-pass gather (dk=32), head-major bf16 k/v ========
// grid = 50000 blocks; slot = bid&7 -> head = slot>>1 (pins each (head) to 2 XCDs
// under the bid%8 round-robin XCD mapping). Block = 4 waves = 4 nodes, one head.
// Wave lanes: eslot = lane>>2 (16 edges in flight), il = lane&3 (8 elems each).
__global__ __launch_bounds__(256) void score128(
    const float* __restrict__ q, const uint4* __restrict__ kh_all,
    const int* __restrict__ rowptr, const int* __restrict__ deg,
    const int* __restrict__ col, float* __restrict__ sc,
    float scale, int n, int nE)
{
    int bid  = blockIdx.x;
    int head = (bid >> 1) & 3;
    int c    = ((bid >> 3) << 1) | (bid & 1);
    int node = c * 4 + (threadIdx.x >> 6);
    int lane = threadIdx.x & 63;
    int eslot = lane >> 2, il = lane & 3;

    const float4* qp = (const float4*)(q + (size_t)node * 128 + head * 32 + il * 8);
    float4 qa = qp[0], qb = qp[1];
    int start = rowptr[node], cnt = deg[node];
    const uint4* kh = kh_all + (size_t)head * n * 4;
    float* sch = sc + (size_t)head * nE;

    for (int t = eslot; t < cnt; t += 16) {
        int d = col[start + t];
        uint4 kw = kh[(size_t)d * 4 + il];
        float2 k0 = bf2f2(kw.x), k1 = bf2f2(kw.y), k2 = bf2f2(kw.z), k3 = bf2f2(kw.w);
        float p = qa.x * k0.x + qa.y * k0.y + qa.z * k1.x + qa.w * k1.y
                + qb.x * k2.x + qb.y * k2.y + qb.z * k3.x + qb.w * k3.y;
        p += __shfl_xor(p, 1);
        p += __shfl_xor(p, 2);
        float e = __expf(p * scale);
        if (il == 0) sch[start + t] = e;
    }
}

template<bool ACCUM, bool ELU>
__global__ __launch_bounds__(256) void accum128(
    const float* __restrict__ sc, const uint4* __restrict__ vh_all,
    const int* __restrict__ rowptr, const int* __restrict__ deg,
    const int* __restrict__ col, float* __restrict__ out,
    float beta, int n, int nE)
{
    int bid  = blockIdx.x;
    int head = (bid >> 1) & 3;
    int c    = ((bid >> 3) << 1) | (bid & 1);
    int node = c * 4 + (threadIdx.x >> 6);
    int lane = threadIdx.x & 63;
    int eslot = lane >> 2, il = lane & 3;

    int start = rowptr[node], cnt = deg[node];
    const uint4* vh = vh_all + (size_t)head * n * 4;
    const float* sch = sc + (size_t)head * nE;

    float l = 0.f;
    float ax[8];
#pragma unroll
    for (int j = 0; j < 8; ++j) ax[j] = 0.f;

    for (int t = eslot; t < cnt; t += 16) {
        int d = col[start + t];
        float e = sch[start + t];
        uint4 vw = vh[(size_t)d * 4 + il];
        float2 v0 = bf2f2(vw.x), v1 = bf2f2(vw.y), v2 = bf2f2(vw.z), v3 = bf2f2(vw.w);
        l += e;
        ax[0] += e * v0.x; ax[1] += e * v0.y;
        ax[2] += e * v1.x; ax[3] += e * v1.y;
        ax[4] += e * v2.x; ax[5] += e * v2.y;
        ax[6] += e * v3.x; ax[7] += e * v3.y;
    }
    // merge 16 eslots (lane bits 2-5)
#pragma unroll
    for (int off = 4; off <= 32; off <<= 1) {
        l += __shfl_xor(l, off);
#pragma unroll
        for (int j = 0; j < 8; ++j) ax[j] += __shfl_xor(ax[j], off);
    }
    if (eslot == 0) {
        float inv = (l > 0.f) ? beta / l : 0.f;
        float* op = out + (size_t)node * 128 + head * 32 + il * 8;
        float r0[8];
        if constexpr (ACCUM) {
            float4 c0 = ((const float4*)op)[0], c1 = ((const float4*)op)[1];
            r0[0] = c0.x + ax[0] * inv; r0[1] = c0.y + ax[1] * inv;
            r0[2] = c0.z + ax[2] * inv; r0[3] = c0.w + ax[3] * inv;
            r0[4] = c1.x + ax[4] * inv; r0[5] = c1.y + ax[5] * inv;
            r0[6] = c1.z + ax[6] * inv; r0[7] = c1.w + ax[7] * inv;
        } else {
#pragma unroll
            for (int j = 0; j < 8; ++j) r0[j] = ax[j] * inv;
        }
        if constexpr (ELU) {
#pragma unroll
            for (int j = 0; j < 8; ++j) r0[j] = elu1(r0[j]);
        }
        ((float4*)op)[0] = make_float4(r0[0], r0[1], r0[2], r0[3]);
        ((float4*)op)[1] = make_float4(r0[4], r0[5], r0[6], r0[7]);
    }
}

// ================= layer-1 two-pass gather (dk=8), head-major bf16 k/v =========
// grid = 12504 blocks; block = 4 waves x 4 nodes = 16 nodes, one head.
// Wave lanes: nsub = lane>>4 (node), eslot = lane&15; full head (16B) per lane.
__global__ __launch_bounds__(256) void score8(
    const float* __restrict__ q, const uint4* __restrict__ kh_all,
    const int* __restrict__ rowptr, const int* __restrict__ deg,
    const int* __restrict__ col, float* __restrict__ sc,
    float scale, int n, int nE)
{
    int bid  = blockIdx.x;
    int head = (bid >> 1) & 3;
    int c    = ((bid >> 3) << 1) | (bid & 1);
    int lane = threadIdx.x & 63;
    int nsub = lane >> 4, eslot = lane & 15;
    int node = c * 16 + (threadIdx.x >> 6) * 4 + nsub;
    if (node >= n) return;

    const float4* qp = (const float4*)(q + (size_t)node * 32 + head * 8);
    float4 qa = qp[0], qb = qp[1];
    int start = rowptr[node], cnt = deg[node];
    const uint4* kh = kh_all + (size_t)head * n;
    float* sch = sc + (size_t)head * nE;

    for (int t = eslot; t < cnt; t += 16) {
        int d = col[start + t];
        uint4 kw = kh[d];
        float2 k0 = bf2f2(kw.x), k1 = bf2f2(kw.y), k2 = bf2f2(kw.z), k3 = bf2f2(kw.w);
        float p = qa.x * k0.x + qa.y * k0.y + qa.z * k1.x + qa.w * k1.y
                + qb.x * k2.x + qb.y * k2.y + qb.z * k3.x + qb.w * k3.y;
        sch[start + t] = __expf(p * scale);
    }
}

template<bool ACCUM>
__global__ __launch_bounds__(256) void accum8(
    const float* __restrict__ sc, const uint4* __restrict__ vh_all,
    const int* __restrict__ rowptr, const int* __restrict__ deg,
    const int* __restrict__ col, float* __restrict__ out,
    float beta, int n, int nE)
{
    int bid  = blockIdx.x;
    int head = (bid >> 1) & 3;
    int c    = ((bid >> 3) << 1) | (bid & 1);
    int lane = threadIdx.x & 63;
    int nsub = lane >> 4, eslot = lane & 15;
    int node = c * 16 + (threadIdx.x >> 6) * 4 + nsub;
    if (node >= n) return;

    int start = rowptr[node], cnt = deg[node];
    const uint4* vh = vh_all + (size_t)head * n;
    const float* sch = sc + (size_t)head * nE;

    float l = 0.f;
    float ax[8];
#pragma unroll
    for (int j = 0; j < 8; ++j) ax[j] = 0.f;

    for (int t = eslot; t < cnt; t += 16) {
        int d = col[start + t];
        float e = sch[start + t];
        uint4 vw = vh[d];
        float2 v0 = bf2f2(vw.x), v1 = bf2f2(vw.y), v2 = bf2f2(vw.z), v3 = bf2f2(vw.w);
        l += e;
        ax[0] += e * v0.x; ax[1] += e * v0.y;
        ax[2] += e * v1.x; ax[3] += e * v1.y;
        ax[4] += e * v2.x; ax[5] += e * v2.y;
        ax[6] += e * v3.x; ax[7] += e * v3.y;
    }
    // merge 16 eslots (lane bits 0-3)
#pragma unroll
    for (int off = 1; off <= 8; off <<= 1) {
        l += __shfl_xor(l, off);
#pragma unroll
        for (int j = 0; j < 8; ++j) ax[j] += __shfl_xor(ax[j], off);
    }
    if (eslot == 0) {
        float inv = (l > 0.f) ? beta / l : 0.f;
        float* op = out + (size_t)node * 32 + head * 8;
        float z[8];
        if constexpr (ACCUM) {
            float4 c0 = ((const float4*)op)[0], c1 = ((const float4*)op)[1];
            z[0] = c0.x + ax[0] * inv; z[1] = c0.y + ax[1] * inv;
            z[2] = c0.z + ax[2] * inv; z[3] = c0.w + ax[3] * inv;
            z[4] = c1.x + ax[4] * inv; z[5] = c1.y + ax[5] * inv;
            z[6] = c1.z + ax[6] * inv; z[7] = c1.w + ax[7] * inv;
        } else {
#pragma unroll
            for (int j = 0; j < 8; ++j) z[j] = ax[j] * inv;
        }
        ((float4*)op)[0] = make_float4(z[0], z[1], z[2], z[3]);
        ((float4*)op)[1] = make_float4(z[4], z[5], z[6], z[7]);
    }
}

// ================= row log_softmax over 32 classes =================
__global__ __launch_bounds__(256) void logsoftmax32(
    const float* __restrict__ lg, float* __restrict__ out, int n)
{
    int t = threadIdx.x;
    int node = blockIdx.x * 8 + t / 32;
    int c = t % 32;
    if (node >= n) return;
    float x = lg[(size_t)node * 32 + c];
    float mx = x;
#pragma unroll
    for (int o = 16; o; o >>= 1) mx = fmaxf(mx, __shfl_xor(mx, o, 32));
    float ex = __expf(x - mx);
    float sm = ex;
#pragma unroll
    for (int o = 16; o; o >>= 1) sm += __shfl_xor(sm, o, 32);
    out[(size_t)node * 32 + c] = x - mx - logf(sm);
}

extern "C" void kernel_launch(void* const* d_in, const int* in_sizes, int n_in,
                              void* d_out, int out_size, void* d_ws, size_t ws_size,
                              hipStream_t stream)
{
    const float* x   = (const float*)d_in[0];
    const float* Wq0 = (const float*)d_in[1];
    const float* bq0 = (const float*)d_in[2];
    const float* Wk0 = (const float*)d_in[3];
    const float* bk0 = (const float*)d_in[4];
    const float* Wv0 = (const float*)d_in[5];
    const float* bv0 = (const float*)d_in[6];
    const float* Wq1 = (const float*)d_in[7];
    const float* bq1 = (const float*)d_in[8];
    const float* Wk1 = (const float*)d_in[9];
    const float* bk1 = (const float*)d_in[10];
    const float* Wv1 = (const float*)d_in[11];
    const float* bv1 = (const float*)d_in[12];
    const int* e0 = (const int*)d_in[13];
    const int* e1 = (const int*)d_in[14];
    const int* e2 = (const int*)d_in[15];
    const int* e3 = (const int*)d_in[16];

    char* w = (char*)d_ws;
    float*          q   = (float*)w;          w += (size_t)N_NODES * HID * 4;   // 25.6 MB
    unsigned short* kb  = (unsigned short*)w; w += (size_t)N_NODES * HID * 2;   // 12.8
    unsigned short* vb  = (unsigned short*)w; w += (size_t)N_NODES * HID * 2;   // 12.8
    float*          acc = (float*)w;          w += (size_t)N_NODES * HID * 4;   // 25.6
    float*          lg  = (float*)w;          w += (size_t)N_NODES * CLS * 4;   // 6.4
    float*          sc  = (float*)w;          w += (size_t)NHEAD * N_EDGES * 4; // 12.8
    int* deg    = (int*)w; w += (size_t)4 * N_NODES * 4;
    int* rowptr = (int*)w; w += (size_t)4 * N_NODES * 4;
    int* col    = (int*)w; w += (size_t)4 * N_EDGES * 4;
    int* bcnt   = (int*)w; w += (size_t)4 * NBUCK * 4;
    int* bbase  = (int*)w; w += (size_t)4 * (NBUCK + 1) * 4;
    int* bcur   = (int*)w; w += (size_t)4 * NBUCK * 4;
    unsigned short* wq0b = (unsigned short*)w; w += (size_t)2 * HID * IN_F * 2;
    unsigned short* wk0b = (unsigned short*)w; w += (size_t)2 * HID * IN_F * 2;
    unsigned short* wv0b = (unsigned short*)w; w += (size_t)2 * HID * IN_F * 2;
    unsigned short* wq1b = (unsigned short*)w; w += (size_t)2 * CLS * IN_F * 2;
    unsigned short* wk1b = (unsigned short*)w; w += (size_t)2 * CLS * IN_F * 2;
    unsigned short* wv1b = (unsigned short*)w; w += (size_t)2 * CLS * IN_F * 2;

    // pairs buffer (25.6 MB) aliases q — only live during CSR build, before any qkv
    int2* pairs = (int2*)q;

    float* out = (float*)d_out;
    const int QB  = (N_NODES / 16 + 3) / 4;    // qkv: 4 waves (16 nodes) / block
    const int GB0 = N_NODES;                   // score/accum128: 50000 blocks exact
    const int GB1 = 12504;                     // score/accum8: ceil to 8-multiple
    const float sc0 = 1.f / sqrtf(32.f), sc1v = 1.f / sqrtf(8.f);

    // ---------- weights -> bf16 ----------
    const int W0 = 2 * HID * IN_F, W1 = 2 * CLS * IN_F;
    conv3<<<dim3((W0 + 255) / 256, 3), 256, 0, stream>>>(Wq0, Wk0, Wv0, wq0b, wk0b, wv0b, W0);
    conv3<<<dim3((W1 + 255) / 256, 3), 256, 0, stream>>>(Wq1, Wk1, Wv1, wq1b, wk1b, wv1b, W1);

    // ---------- build 4 CSRs (bucket counting sort) ----------
    hipMemsetAsync(bcnt, 0, (size_t)4 * NBUCK * 4, stream);
    bucket_hist<<<dim3(256, 4), 256, 0, stream>>>(e0, e1, e2, e3, bcnt, N_EDGES);
    bucket_scan<<<4, 256, 0, stream>>>(bcnt, bbase, bcur);
    pass1_scatter<<<dim3((N_EDGES + TILE - 1) / TILE, 4), 256, 0, stream>>>(
        e0, e1, e2, e3, bcur, pairs, N_EDGES);
    pass2_place<<<dim3(NBUCK, 4), 256, 0, stream>>>(
        pairs, bbase, rowptr, deg, col, N_EDGES, N_NODES);

    // ================= layer 0 (A=128, dk=32) =================
    for (int hop = 0; hop < 2; ++hop) {
        qkv_mfma<HID, 32, false><<<QB, 256, 0, stream>>>(
            x,
            wq0b + (size_t)hop * HID * IN_F, bq0 + (size_t)hop * HID,
            wk0b + (size_t)hop * HID * IN_F, bk0 + (size_t)hop * HID,
            wv0b + (size_t)hop * HID * IN_F, bv0 + (size_t)hop * HID,
            q, kb, vb, N_NODES);
        const int* rp = rowptr + (size_t)hop * N_NODES;
        const int* dg = deg + (size_t)hop * N_NODES;
        const int* cl = col + (size_t)hop * N_EDGES;
        score128<<<GB0, 256, 0, stream>>>(
            q, (const uint4*)kb, rp, dg, cl, sc, sc0, N_NODES, N_EDGES);
        if (hop == 0)
            accum128<false, false><<<GB0, 256, 0, stream>>>(
                sc, (const uint4*)vb, rp, dg, cl, acc, 1.0f, N_NODES, N_EDGES);
        else
            accum128<true, true><<<GB0, 256, 0, stream>>>(
                sc, (const uint4*)vb, rp, dg, cl, acc, 0.5f, N_NODES, N_EDGES);
    }

    // ================= layer 1 (A=32, dk=8); ELU fused into qkv input ==========
    for (int hop = 0; hop < 2; ++hop) {
        qkv_mfma<CLS, 8, true><<<QB, 256, 0, stream>>>(
            acc,
            wq1b + (size_t)hop * CLS * IN_F, bq1 + (size_t)hop * CLS,
            wk1b + (size_t)hop * CLS * IN_F, bk1 + (size_t)hop * CLS,
            wv1b + (size_t)hop * CLS * IN_F, bv1 + (size_t)hop * CLS,
            q, kb, vb, N_NODES);
        const int* rp = rowptr + (size_t)(2 + hop) * N_NODES;
        const int* dg = deg + (size_t)(2 + hop) * N_NODES;
        const int* cl = col + (size_t)(2 + hop) * N_EDGES;
        score8<<<GB1, 256, 0, stream>>>(
            q, (const uint4*)kb, rp, dg, cl, sc, sc1v, N_NODES, N_EDGES);
        if (hop == 0)
            accum8<false><<<GB1, 256, 0, stream>>>(
                sc, (const uint4*)vb, rp, dg, cl, lg, 1.0f, N_NODES, N_EDGES);
        else
            accum8<true><<<GB1, 256, 0, stream>>>(
                sc, (const uint4*)vb, rp, dg, cl, lg, 0.5f, N_NODES, N_EDGES);
    }
    logsoftmax32<<<(N_NODES + 7) / 8, 256, 0, stream>>>(lg, out, N_NODES);
}

// Round 8
// 383.482 us; speedup vs baseline: 1.6344x; 1.6344x over previous
//
#include <hip/hip_runtime.h>
#include <hip/hip_bf16.h>
#include <math.h>

#define N_NODES 50000
#define N_EDGES 800000
#define IN_F    128
#define HID     128
#define CLS     32
#define NHEAD   4
#define NBUCK   196        // ceil(N_NODES / 256)

typedef __attribute__((ext_vector_type(8))) short  short8;
typedef __attribute__((ext_vector_type(4))) float  floatx4;

// ---------- f32 -> bf16 (RNE) ----------
static __device__ __forceinline__ unsigned short f2bf(float f) {
    unsigned int u = __float_as_uint(f);
    return (unsigned short)((u + 0x7fffu + ((u >> 16) & 1u)) >> 16);
}
static __device__ __forceinline__ float2 bf2f2(unsigned int u) {
    return make_float2(__uint_as_float(u << 16), __uint_as_float(u & 0xffff0000u));
}
static __device__ __forceinline__ float elu1(float x) {
    return x > 0.f ? x : expm1f(x);
}

// ---------- weight conversion: all 6 matrices in one launch ----------
__global__ __launch_bounds__(256) void conv6(
    const float* __restrict__ a0, const float* __restrict__ a1, const float* __restrict__ a2,
    const float* __restrict__ a3, const float* __restrict__ a4, const float* __restrict__ a5,
    unsigned short* __restrict__ o0, unsigned short* __restrict__ o1, unsigned short* __restrict__ o2,
    unsigned short* __restrict__ o3, unsigned short* __restrict__ o4, unsigned short* __restrict__ o5,
    int cBig, int cSmall)
{
    const float* srcs[6] = {a0, a1, a2, a3, a4, a5};
    unsigned short* dsts[6] = {o0, o1, o2, o3, o4, o5};
    int s = blockIdx.y;
    int count = (s < 3) ? cBig : cSmall;
    int i = blockIdx.x * 256 + threadIdx.x;
    if (i < count) dsts[s][i] = f2bf(srcs[s][i]);
}

// ================= CSR build: 2-pass coarse-bucket counting sort =================
__global__ __launch_bounds__(256) void bucket_hist(
    const int* __restrict__ e0, const int* __restrict__ e1,
    const int* __restrict__ e2, const int* __restrict__ e3,
    int* __restrict__ bcnt, int nE)
{
    const int s = blockIdx.y;
    const int* ep = (s == 0) ? e0 : (s == 1) ? e1 : (s == 2) ? e2 : e3;
    __shared__ int h[NBUCK];
    for (int i = threadIdx.x; i < NBUCK; i += 256) h[i] = 0;
    __syncthreads();
    for (int e = blockIdx.x * 256 + threadIdx.x; e < nE; e += gridDim.x * 256)
        atomicAdd(&h[ep[e] >> 8], 1);
    __syncthreads();
    for (int i = threadIdx.x; i < NBUCK; i += 256)
        if (h[i]) atomicAdd(&bcnt[s * NBUCK + i], h[i]);
}

__global__ __launch_bounds__(256) void bucket_scan(
    const int* __restrict__ bcnt, int* __restrict__ bbase, int* __restrict__ bcur)
{
    int s = blockIdx.x;
    __shared__ int tmp[256];
    int v = (threadIdx.x < NBUCK) ? bcnt[s * NBUCK + threadIdx.x] : 0;
    tmp[threadIdx.x] = v; __syncthreads();
    for (int o = 1; o < 256; o <<= 1) {
        int t = (threadIdx.x >= o) ? tmp[threadIdx.x - o] : 0;
        __syncthreads(); tmp[threadIdx.x] += t; __syncthreads();
    }
    int excl = tmp[threadIdx.x] - v;
    if (threadIdx.x < NBUCK) {
        bbase[s * (NBUCK + 1) + threadIdx.x] = excl;
        bcur[s * NBUCK + threadIdx.x] = excl;
    }
    if (threadIdx.x == NBUCK - 1)
        bbase[s * (NBUCK + 1) + NBUCK] = excl + v;
}

// pass 1: packed (src&255)<<16 | dst  (dst < 65536 since N=50000)
#define TILE 8192
__global__ __launch_bounds__(256) void pass1_scatter(
    const int* __restrict__ e0, const int* __restrict__ e1,
    const int* __restrict__ e2, const int* __restrict__ e3,
    int* __restrict__ bcur, unsigned int* __restrict__ pairs, int nE)
{
    const int s = blockIdx.y;
    const int* ep = (s == 0) ? e0 : (s == 1) ? e1 : (s == 2) ? e2 : e3;
    const int tile0 = blockIdx.x * TILE;
    __shared__ int hist[NBUCK], base[NBUCK], cur[NBUCK];
    for (int i = threadIdx.x; i < NBUCK; i += 256) { hist[i] = 0; cur[i] = 0; }
    __syncthreads();
    for (int i = threadIdx.x; i < TILE; i += 256) {
        int e = tile0 + i;
        if (e < nE) atomicAdd(&hist[ep[e] >> 8], 1);
    }
    __syncthreads();
    for (int i = threadIdx.x; i < NBUCK; i += 256)
        base[i] = hist[i] ? atomicAdd(&bcur[s * NBUCK + i], hist[i]) : 0;
    __syncthreads();
    unsigned int* pp = pairs + (size_t)s * nE;
    for (int i = threadIdx.x; i < TILE; i += 256) {
        int e = tile0 + i;
        if (e < nE) {
            int src = ep[e], dst = ep[e + nE];
            int b = src >> 8;
            int r = atomicAdd(&cur[b], 1);
            pp[base[b] + r] = ((unsigned int)(src & 255) << 16) | (unsigned int)dst;
        }
    }
}

__global__ __launch_bounds__(256) void pass2_place(
    const unsigned int* __restrict__ pairs, const int* __restrict__ bbase,
    int* __restrict__ rowptr, int* __restrict__ deg, int* __restrict__ col,
    int nE, int n)
{
    const int s = blockIdx.y, b = blockIdx.x;
    const int base0 = bbase[s * (NBUCK + 1) + b];
    const int ecnt  = bbase[s * (NBUCK + 1) + b + 1] - base0;
    const unsigned int* pp = pairs + (size_t)s * nE + base0;
    __shared__ int hist[256], cur[256];
    hist[threadIdx.x] = 0;
    __syncthreads();
    for (int i = threadIdx.x; i < ecnt; i += 256)
        atomicAdd(&hist[(pp[i] >> 16) & 255], 1);
    __syncthreads();
    int v = hist[threadIdx.x];
    cur[threadIdx.x] = v; __syncthreads();
    for (int o = 1; o < 256; o <<= 1) {
        int t = (threadIdx.x >= o) ? cur[threadIdx.x - o] : 0;
        __syncthreads(); cur[threadIdx.x] += t; __syncthreads();
    }
    int excl = cur[threadIdx.x] - v;
    int node = b * 256 + threadIdx.x;
    if (node < n) {
        rowptr[(size_t)s * n + node] = base0 + excl;
        deg[(size_t)s * n + node] = v;
    }
    __syncthreads();
    cur[threadIdx.x] = excl;
    __syncthreads();
    int* colp = col + (size_t)s * nE + base0;
    for (int i = threadIdx.x; i < ecnt; i += 256) {
        unsigned int pr = pp[i];
        int r = atomicAdd(&cur[(pr >> 16) & 255], 1);
        colp[r] = (int)(pr & 0xffffu);
    }
}

// ================= MFMA Q/K/V projection (both hops in one kernel) =============
static __device__ __forceinline__ short8 pack8(const float* p) {
    float4 a = *(const float4*)p;
    float4 b = *(const float4*)(p + 4);
    short8 v;
    v[0] = (short)f2bf(a.x); v[1] = (short)f2bf(a.y);
    v[2] = (short)f2bf(a.z); v[3] = (short)f2bf(a.w);
    v[4] = (short)f2bf(b.x); v[5] = (short)f2bf(b.y);
    v[6] = (short)f2bf(b.z); v[7] = (short)f2bf(b.w);
    return v;
}

template<int NT, int A, bool BF>
__device__ __forceinline__ void mat_mfma(
    const short8* xf, const unsigned short* W, const float* b,
    void* o, int node0, int r, int kg)
{
    floatx4 acc[NT];
#pragma unroll
    for (int nt = 0; nt < NT; ++nt) {
        float bb = b[nt * 16 + r];
        acc[nt] = (floatx4){bb, bb, bb, bb};
    }
#pragma unroll
    for (int ks = 0; ks < 4; ++ks) {
#pragma unroll
        for (int nt = 0; nt < NT; ++nt) {
            short8 wf = *(const short8*)((const short*)W + (size_t)(nt * 16 + r) * IN_F + ks * 32 + kg * 8);
            acc[nt] = __builtin_amdgcn_mfma_f32_16x16x32_bf16(xf[ks], wf, acc[nt], 0, 0, 0);
        }
    }
#pragma unroll
    for (int nt = 0; nt < NT; ++nt)
#pragma unroll
        for (int reg = 0; reg < 4; ++reg) {
            size_t idx = (size_t)(node0 + kg * 4 + reg) * A + nt * 16 + r;
            if constexpr (BF) ((unsigned short*)o)[idx] = f2bf(acc[nt][reg]);
            else              ((float*)o)[idx] = acc[nt][reg];
        }
}

template<int A>
__global__ __launch_bounds__(256) void qkv2_mfma(
    const float* __restrict__ x,
    const unsigned short* __restrict__ Wq, const float* __restrict__ bq,
    const unsigned short* __restrict__ Wk, const float* __restrict__ bk,
    const unsigned short* __restrict__ Wv, const float* __restrict__ bv,
    float* __restrict__ q0, float* __restrict__ q1,
    unsigned short* __restrict__ k0, unsigned short* __restrict__ k1,
    unsigned short* __restrict__ v0, unsigned short* __restrict__ v1,
    int n)
{
    constexpr int NT = A / 16;
    const int wave = threadIdx.x >> 6;
    const int lane = threadIdx.x & 63;
    const int node0 = blockIdx.x * 64 + wave * 16;
    if (node0 >= n) return;
    const int r  = lane & 15;
    const int kg = lane >> 4;

    short8 xf[4];
    const float* xr = x + (size_t)(node0 + r) * IN_F + kg * 8;
#pragma unroll
    for (int ks = 0; ks < 4; ++ks) xf[ks] = pack8(xr + ks * 32);

    mat_mfma<NT, A, false>(xf, Wq,                    bq,     q0, node0, r, kg);
    mat_mfma<NT, A, true >(xf, Wk,                    bk,     k0, node0, r, kg);
    mat_mfma<NT, A, true >(xf, Wv,                    bv,     v0, node0, r, kg);
    mat_mfma<NT, A, false>(xf, Wq + (size_t)A * IN_F, bq + A, q1, node0, r, kg);
    mat_mfma<NT, A, true >(xf, Wk + (size_t)A * IN_F, bk + A, k1, node0, r, kg);
    mat_mfma<NT, A, true >(xf, Wv + (size_t)A * IN_F, bv + A, v1, node0, r, kg);
}

// ================= fused per-node gather phases =================
static __device__ __forceinline__ float dot8(float4 qa, float4 qb, uint4 kw) {
    float2 k0 = bf2f2(kw.x), k1 = bf2f2(kw.y), k2 = bf2f2(kw.z), k3 = bf2f2(kw.w);
    return qa.x * k0.x + qa.y * k0.y + qa.z * k1.x + qa.w * k1.y
         + qb.x * k2.x + qb.y * k2.y + qb.z * k3.x + qb.w * k3.y;
}

// layer-0 phase: eslot = lane>>4 (4 edges in flight, 2x unrolled), il = lane&15
__device__ __forceinline__ void gat_phase128(
    const float* __restrict__ q, const uint4* __restrict__ kb,
    const uint4* __restrict__ vb,
    const int* __restrict__ rowptr, const int* __restrict__ deg,
    const int* __restrict__ col,
    int wid, int eslot, int il, float scale, float* r)
{
    const float4* qp = (const float4*)(q + (size_t)wid * 128 + il * 8);
    float4 qa = qp[0], qb = qp[1];
    int start = rowptr[wid], cnt = deg[wid];
    float l = 0.f;
    float ax[8];
#pragma unroll
    for (int j = 0; j < 8; ++j) ax[j] = 0.f;

    int t = eslot;
    for (; t + 4 < cnt; t += 8) {       // 2 edges per eslot in flight
        int d0 = col[start + t], d1 = col[start + t + 4];
        uint4 kw0 = kb[(size_t)d0 * 16 + il];
        uint4 kw1 = kb[(size_t)d1 * 16 + il];
        uint4 vw0 = vb[(size_t)d0 * 16 + il];
        uint4 vw1 = vb[(size_t)d1 * 16 + il];
        float p0 = dot8(qa, qb, kw0);
        float p1 = dot8(qa, qb, kw1);
        p0 += __shfl_xor(p0, 1); p0 += __shfl_xor(p0, 2);
        p1 += __shfl_xor(p1, 1); p1 += __shfl_xor(p1, 2);
        float e0 = __expf(p0 * scale);
        float e1 = __expf(p1 * scale);
        l += e0 + e1;
        float2 a0 = bf2f2(vw0.x), a1 = bf2f2(vw0.y), a2 = bf2f2(vw0.z), a3 = bf2f2(vw0.w);
        float2 b0 = bf2f2(vw1.x), b1 = bf2f2(vw1.y), b2 = bf2f2(vw1.z), b3 = bf2f2(vw1.w);
        ax[0] += e0 * a0.x + e1 * b0.x; ax[1] += e0 * a0.y + e1 * b0.y;
        ax[2] += e0 * a1.x + e1 * b1.x; ax[3] += e0 * a1.y + e1 * b1.y;
        ax[4] += e0 * a2.x + e1 * b2.x; ax[5] += e0 * a2.y + e1 * b2.y;
        ax[6] += e0 * a3.x + e1 * b3.x; ax[7] += e0 * a3.y + e1 * b3.y;
    }
    for (; t < cnt; t += 4) {
        int d = col[start + t];
        uint4 kw = kb[(size_t)d * 16 + il];
        uint4 vw = vb[(size_t)d * 16 + il];
        float p = dot8(qa, qb, kw);
        p += __shfl_xor(p, 1); p += __shfl_xor(p, 2);
        float e = __expf(p * scale);
        l += e;
        float2 a0 = bf2f2(vw.x), a1 = bf2f2(vw.y), a2 = bf2f2(vw.z), a3 = bf2f2(vw.w);
        ax[0] += e * a0.x; ax[1] += e * a0.y;
        ax[2] += e * a1.x; ax[3] += e * a1.y;
        ax[4] += e * a2.x; ax[5] += e * a2.y;
        ax[6] += e * a3.x; ax[7] += e * a3.y;
    }
#pragma unroll
    for (int off = 16; off <= 32; off <<= 1) {
        l += __shfl_xor(l, off);
#pragma unroll
        for (int j = 0; j < 8; ++j) ax[j] += __shfl_xor(ax[j], off);
    }
    float inv = (l > 0.f) ? 1.f / l : 0.f;
#pragma unroll
    for (int j = 0; j < 8; ++j) r[j] = ax[j] * inv;
}

// both layer-0 hops; ELU'd sum written once
__global__ __launch_bounds__(256) void gat2_128(
    const float* __restrict__ q0, const float* __restrict__ q1,
    const uint4* __restrict__ k0, const uint4* __restrict__ v0,
    const uint4* __restrict__ k1, const uint4* __restrict__ v1,
    const int* __restrict__ rp0, const int* __restrict__ dg0, const int* __restrict__ cl0,
    const int* __restrict__ rp1, const int* __restrict__ dg1, const int* __restrict__ cl1,
    float* __restrict__ out, float scale, int n)
{
    int wid  = (blockIdx.x * 256 + threadIdx.x) >> 6;
    int lane = threadIdx.x & 63;
    if (wid >= n) return;
    int eslot = lane >> 4, il = lane & 15;

    float r0[8], r1[8];
    gat_phase128(q0, k0, v0, rp0, dg0, cl0, wid, eslot, il, scale, r0);
    gat_phase128(q1, k1, v1, rp1, dg1, cl1, wid, eslot, il, scale, r1);

    if (eslot == 0) {
        float z[8];
#pragma unroll
        for (int j = 0; j < 8; ++j) z[j] = elu1(r0[j] + 0.5f * r1[j]);
        float4* op = (float4*)(out + (size_t)wid * 128 + il * 8);
        op[0] = make_float4(z[0], z[1], z[2], z[3]);
        op[1] = make_float4(z[4], z[5], z[6], z[7]);
    }
}

// layer-1 phase: eslot = lane>>2 (16 edges in flight), il = lane&3 = head
__device__ __forceinline__ void gat_phase32(
    const float* __restrict__ q, const uint4* __restrict__ kb,
    const uint4* __restrict__ vb,
    const int* __restrict__ rowptr, const int* __restrict__ deg,
    const int* __restrict__ col,
    int wid, int eslot, int il, float scale, float* r)
{
    const float4* qp = (const float4*)(q + (size_t)wid * 32 + il * 8);
    float4 qa = qp[0], qb = qp[1];
    int start = rowptr[wid], cnt = deg[wid];
    float l = 0.f;
    float ax[8];
#pragma unroll
    for (int j = 0; j < 8; ++j) ax[j] = 0.f;

    for (int t = eslot; t < cnt; t += 16) {
        int d = col[start + t];
        uint4 kw = kb[(size_t)d * 4 + il];
        uint4 vw = vb[(size_t)d * 4 + il];
        float p = dot8(qa, qb, kw);
        float e = __expf(p * scale);
        l += e;
        float2 a0 = bf2f2(vw.x), a1 = bf2f2(vw.y), a2 = bf2f2(vw.z), a3 = bf2f2(vw.w);
        ax[0] += e * a0.x; ax[1] += e * a0.y;
        ax[2] += e * a1.x; ax[3] += e * a1.y;
        ax[4] += e * a2.x; ax[5] += e * a2.y;
        ax[6] += e * a3.x; ax[7] += e * a3.y;
    }
#pragma unroll
    for (int off = 4; off <= 32; off <<= 1) {
        l += __shfl_xor(l, off);
#pragma unroll
        for (int j = 0; j < 8; ++j) ax[j] += __shfl_xor(ax[j], off);
    }
    float inv = (l > 0.f) ? 1.f / l : 0.f;
#pragma unroll
    for (int j = 0; j < 8; ++j) r[j] = ax[j] * inv;
}

// both layer-1 hops + fused log_softmax -> final output
__global__ __launch_bounds__(256) void gat2_32(
    const float* __restrict__ q0, const float* __restrict__ q1,
    const uint4* __restrict__ k0, const uint4* __restrict__ v0,
    const uint4* __restrict__ k1, const uint4* __restrict__ v1,
    const int* __restrict__ rp0, const int* __restrict__ dg0, const int* __restrict__ cl0,
    const int* __restrict__ rp1, const int* __restrict__ dg1, const int* __restrict__ cl1,
    float* __restrict__ outp, float scale, int n)
{
    int wid  = (blockIdx.x * 256 + threadIdx.x) >> 6;
    int lane = threadIdx.x & 63;
    if (wid >= n) return;
    int eslot = lane >> 2, il = lane & 3;

    float r0[8], r1[8];
    gat_phase32(q0, k0, v0, rp0, dg0, cl0, wid, eslot, il, scale, r0);
    gat_phase32(q1, k1, v1, rp1, dg1, cl1, wid, eslot, il, scale, r1);

    if (eslot == 0) {
        float z[8];
#pragma unroll
        for (int j = 0; j < 8; ++j) z[j] = r0[j] + 0.5f * r1[j];
        float mx = z[0];
#pragma unroll
        for (int j = 1; j < 8; ++j) mx = fmaxf(mx, z[j]);
        mx = fmaxf(mx, __shfl_xor(mx, 1));
        mx = fmaxf(mx, __shfl_xor(mx, 2));
        float sm = 0.f;
#pragma unroll
        for (int j = 0; j < 8; ++j) sm += __expf(z[j] - mx);
        sm += __shfl_xor(sm, 1);
        sm += __shfl_xor(sm, 2);
        float lse = mx + logf(sm);
        float4* op = (float4*)(outp + (size_t)wid * 32 + il * 8);
        op[0] = make_float4(z[0] - lse, z[1] - lse, z[2] - lse, z[3] - lse);
        op[1] = make_float4(z[4] - lse, z[5] - lse, z[6] - lse, z[7] - lse);
    }
}

extern "C" void kernel_launch(void* const* d_in, const int* in_sizes, int n_in,
                              void* d_out, int out_size, void* d_ws, size_t ws_size,
                              hipStream_t stream)
{
    const float* x   = (const float*)d_in[0];
    const float* Wq0 = (const float*)d_in[1];
    const float* bq0 = (const float*)d_in[2];
    const float* Wk0 = (const float*)d_in[3];
    const float* bk0 = (const float*)d_in[4];
    const float* Wv0 = (const float*)d_in[5];
    const float* bv0 = (const float*)d_in[6];
    const float* Wq1 = (const float*)d_in[7];
    const float* bq1 = (const float*)d_in[8];
    const float* Wk1 = (const float*)d_in[9];
    const float* bk1 = (const float*)d_in[10];
    const float* Wv1 = (const float*)d_in[11];
    const float* bv1 = (const float*)d_in[12];
    const int* e0 = (const int*)d_in[13];
    const int* e1 = (const int*)d_in[14];
    const int* e2 = (const int*)d_in[15];
    const int* e3 = (const int*)d_in[16];

    char* w = (char*)d_ws;
    float*          q0  = (float*)w;          w += (size_t)N_NODES * HID * 4;   // 25.6 MB
    float*          q1  = (float*)w;          w += (size_t)N_NODES * HID * 4;   // 25.6
    unsigned short* k0b = (unsigned short*)w; w += (size_t)N_NODES * HID * 2;   // 12.8
    unsigned short* v0b = (unsigned short*)w; w += (size_t)N_NODES * HID * 2;
    unsigned short* k1b = (unsigned short*)w; w += (size_t)N_NODES * HID * 2;
    unsigned short* v1b = (unsigned short*)w; w += (size_t)N_NODES * HID * 2;
    float*          acc = (float*)w;          w += (size_t)N_NODES * HID * 4;   // 25.6
    int* deg    = (int*)w; w += (size_t)4 * N_NODES * 4;
    int* rowptr = (int*)w; w += (size_t)4 * N_NODES * 4;
    int* col    = (int*)w; w += (size_t)4 * N_EDGES * 4;
    int* bcnt   = (int*)w; w += (size_t)4 * NBUCK * 4;
    int* bbase  = (int*)w; w += (size_t)4 * (NBUCK + 1) * 4;
    int* bcur   = (int*)w; w += (size_t)4 * NBUCK * 4;
    unsigned short* wq0b = (unsigned short*)w; w += (size_t)2 * HID * IN_F * 2;
    unsigned short* wk0b = (unsigned short*)w; w += (size_t)2 * HID * IN_F * 2;
    unsigned short* wv0b = (unsigned short*)w; w += (size_t)2 * HID * IN_F * 2;
    unsigned short* wq1b = (unsigned short*)w; w += (size_t)2 * CLS * IN_F * 2;
    unsigned short* wk1b = (unsigned short*)w; w += (size_t)2 * CLS * IN_F * 2;
    unsigned short* wv1b = (unsigned short*)w; w += (size_t)2 * CLS * IN_F * 2;

    // aliases: pairs (12.8 MB) lives in q0 during CSR build (before any qkv).
    unsigned int* pairs = (unsigned int*)q0;
    // layer-1 buffers alias layer-0 buffers (dead after gat2_128):
    float*          qA0 = q0;                                  // 6.4 MB
    float*          qA1 = q0 + (size_t)N_NODES * CLS;          // 6.4 MB
    unsigned short* kA0 = k0b;                                 // 3.2 MB each
    unsigned short* vA0 = v0b;
    unsigned short* kA1 = k1b;
    unsigned short* vA1 = v1b;

    float* out = (float*)d_out;
    const int NB = (N_NODES + 3) / 4;
    const int QB = (N_NODES / 16 + 3) / 4;
    const float sc0 = 1.f / sqrtf(32.f), sc1 = 1.f / sqrtf(8.f);

    // ---------- weights -> bf16 (1 launch) ----------
    const int W0 = 2 * HID * IN_F, W1 = 2 * CLS * IN_F;
    conv6<<<dim3((W0 + 255) / 256, 6), 256, 0, stream>>>(
        Wq0, Wk0, Wv0, Wq1, Wk1, Wv1, wq0b, wk0b, wv0b, wq1b, wk1b, wv1b, W0, W1);

    // ---------- build 4 CSRs ----------
    hipMemsetAsync(bcnt, 0, (size_t)4 * NBUCK * 4, stream);
    bucket_hist<<<dim3(256, 4), 256, 0, stream>>>(e0, e1, e2, e3, bcnt, N_EDGES);
    bucket_scan<<<4, 256, 0, stream>>>(bcnt, bbase, bcur);
    pass1_scatter<<<dim3((N_EDGES + TILE - 1) / TILE, 4), 256, 0, stream>>>(
        e0, e1, e2, e3, bcur, pairs, N_EDGES);
    pass2_place<<<dim3(NBUCK, 4), 256, 0, stream>>>(
        pairs, bbase, rowptr, deg, col, N_EDGES, N_NODES);

    // ================= layer 0: qkv both hops, gather both hops =================
    qkv2_mfma<HID><<<QB, 256, 0, stream>>>(
        x, wq0b, bq0, wk0b, bk0, wv0b, bv0,
        q0, q1, k0b, k1b, v0b, v1b, N_NODES);
    gat2_128<<<NB, 256, 0, stream>>>(
        q0, q1,
        (const uint4*)k0b, (const uint4*)v0b, (const uint4*)k1b, (const uint4*)v1b,
        rowptr,            deg,            col,
        rowptr + N_NODES,  deg + N_NODES,  col + N_EDGES,
        acc, sc0, N_NODES);

    // ================= layer 1: qkv both hops, gather + logsoftmax ==============
    qkv2_mfma<CLS><<<QB, 256, 0, stream>>>(
        acc, wq1b, bq1, wk1b, bk1, wv1b, bv1,
        qA0, qA1, kA0, kA1, vA0, vA1, N_NODES);
    gat2_32<<<NB, 256, 0, stream>>>(
        qA0, qA1,
        (const uint4*)kA0, (const uint4*)vA0, (const uint4*)kA1, (const uint4*)vA1,
        rowptr + 2 * N_NODES, deg + 2 * N_NODES, col + (size_t)2 * N_EDGES,
        rowptr + 3 * N_NODES, deg + 3 * N_NODES, col + (size_t)3 * N_EDGES,
        out, sc1, N_NODES);
}

// Round 9
// 380.442 us; speedup vs baseline: 1.6474x; 1.0080x over previous
//
#include <hip/hip_runtime.h>
#include <hip/hip_bf16.h>
#include <math.h>

#define N_NODES 50000
#define N_EDGES 800000
#define IN_F    128
#define HID     128
#define CLS     32
#define NHEAD   4
#define NBUCK   196        // ceil(N_NODES / 256)

typedef __attribute__((ext_vector_type(8))) short  short8;
typedef __attribute__((ext_vector_type(4))) float  floatx4;
typedef _Float16 h2 __attribute__((ext_vector_type(2)));

// ---------- conversions ----------
static __device__ __forceinline__ unsigned short f2bf(float f) {
    unsigned int u = __float_as_uint(f);
    return (unsigned short)((u + 0x7fffu + ((u >> 16) & 1u)) >> 16);
}
static __device__ __forceinline__ unsigned short f2h(float f) {
    return __builtin_bit_cast(unsigned short, (_Float16)f);
}
static __device__ __forceinline__ h2 uh2(unsigned int u) {
    return __builtin_bit_cast(h2, u);
}
static __device__ __forceinline__ float elu1(float x) {
    return x > 0.f ? x : expm1f(x);
}

// packed-f16 8-elem dot: 4 pk_fma + f32 fold
static __device__ __forceinline__ float dot8h(uint4 qw, uint4 kw) {
    h2 d = uh2(qw.x) * uh2(kw.x);
    d += uh2(qw.y) * uh2(kw.y);
    d += uh2(qw.z) * uh2(kw.z);
    d += uh2(qw.w) * uh2(kw.w);
    return (float)d.x + (float)d.y;
}

// ---------- weight conversion: all 6 matrices in one launch ----------
__global__ __launch_bounds__(256) void conv6(
    const float* __restrict__ a0, const float* __restrict__ a1, const float* __restrict__ a2,
    const float* __restrict__ a3, const float* __restrict__ a4, const float* __restrict__ a5,
    unsigned short* __restrict__ o0, unsigned short* __restrict__ o1, unsigned short* __restrict__ o2,
    unsigned short* __restrict__ o3, unsigned short* __restrict__ o4, unsigned short* __restrict__ o5,
    int cBig, int cSmall)
{
    const float* srcs[6] = {a0, a1, a2, a3, a4, a5};
    unsigned short* dsts[6] = {o0, o1, o2, o3, o4, o5};
    int s = blockIdx.y;
    int count = (s < 3) ? cBig : cSmall;
    int i = blockIdx.x * 256 + threadIdx.x;
    if (i < count) dsts[s][i] = f2bf(srcs[s][i]);
}

// ================= CSR build: 2-pass coarse-bucket counting sort =================
__global__ __launch_bounds__(256) void bucket_hist(
    const int* __restrict__ e0, const int* __restrict__ e1,
    const int* __restrict__ e2, const int* __restrict__ e3,
    int* __restrict__ bcnt, int nE)
{
    const int s = blockIdx.y;
    const int* ep = (s == 0) ? e0 : (s == 1) ? e1 : (s == 2) ? e2 : e3;
    __shared__ int h[NBUCK];
    for (int i = threadIdx.x; i < NBUCK; i += 256) h[i] = 0;
    __syncthreads();
    for (int e = blockIdx.x * 256 + threadIdx.x; e < nE; e += gridDim.x * 256)
        atomicAdd(&h[ep[e] >> 8], 1);
    __syncthreads();
    for (int i = threadIdx.x; i < NBUCK; i += 256)
        if (h[i]) atomicAdd(&bcnt[s * NBUCK + i], h[i]);
}

__global__ __launch_bounds__(256) void bucket_scan(
    const int* __restrict__ bcnt, int* __restrict__ bbase, int* __restrict__ bcur)
{
    int s = blockIdx.x;
    __shared__ int tmp[256];
    int v = (threadIdx.x < NBUCK) ? bcnt[s * NBUCK + threadIdx.x] : 0;
    tmp[threadIdx.x] = v; __syncthreads();
    for (int o = 1; o < 256; o <<= 1) {
        int t = (threadIdx.x >= o) ? tmp[threadIdx.x - o] : 0;
        __syncthreads(); tmp[threadIdx.x] += t; __syncthreads();
    }
    int excl = tmp[threadIdx.x] - v;
    if (threadIdx.x < NBUCK) {
        bbase[s * (NBUCK + 1) + threadIdx.x] = excl;
        bcur[s * NBUCK + threadIdx.x] = excl;
    }
    if (threadIdx.x == NBUCK - 1)
        bbase[s * (NBUCK + 1) + NBUCK] = excl + v;
}

// pass 1: packed (src&255)<<16 | dst  (dst < 65536 since N=50000)
#define TILE 8192
__global__ __launch_bounds__(256) void pass1_scatter(
    const int* __restrict__ e0, const int* __restrict__ e1,
    const int* __restrict__ e2, const int* __restrict__ e3,
    int* __restrict__ bcur, unsigned int* __restrict__ pairs, int nE)
{
    const int s = blockIdx.y;
    const int* ep = (s == 0) ? e0 : (s == 1) ? e1 : (s == 2) ? e2 : e3;
    const int tile0 = blockIdx.x * TILE;
    __shared__ int hist[NBUCK], base[NBUCK], cur[NBUCK];
    for (int i = threadIdx.x; i < NBUCK; i += 256) { hist[i] = 0; cur[i] = 0; }
    __syncthreads();
    for (int i = threadIdx.x; i < TILE; i += 256) {
        int e = tile0 + i;
        if (e < nE) atomicAdd(&hist[ep[e] >> 8], 1);
    }
    __syncthreads();
    for (int i = threadIdx.x; i < NBUCK; i += 256)
        base[i] = hist[i] ? atomicAdd(&bcur[s * NBUCK + i], hist[i]) : 0;
    __syncthreads();
    unsigned int* pp = pairs + (size_t)s * nE;
    for (int i = threadIdx.x; i < TILE; i += 256) {
        int e = tile0 + i;
        if (e < nE) {
            int src = ep[e], dst = ep[e + nE];
            int b = src >> 8;
            int r = atomicAdd(&cur[b], 1);
            pp[base[b] + r] = ((unsigned int)(src & 255) << 16) | (unsigned int)dst;
        }
    }
}

__global__ __launch_bounds__(256) void pass2_place(
    const unsigned int* __restrict__ pairs, const int* __restrict__ bbase,
    int* __restrict__ rowptr, int* __restrict__ deg, int* __restrict__ col,
    int nE, int n)
{
    const int s = blockIdx.y, b = blockIdx.x;
    const int base0 = bbase[s * (NBUCK + 1) + b];
    const int ecnt  = bbase[s * (NBUCK + 1) + b + 1] - base0;
    const unsigned int* pp = pairs + (size_t)s * nE + base0;
    __shared__ int hist[256], cur[256];
    hist[threadIdx.x] = 0;
    __syncthreads();
    for (int i = threadIdx.x; i < ecnt; i += 256)
        atomicAdd(&hist[(pp[i] >> 16) & 255], 1);
    __syncthreads();
    int v = hist[threadIdx.x];
    cur[threadIdx.x] = v; __syncthreads();
    for (int o = 1; o < 256; o <<= 1) {
        int t = (threadIdx.x >= o) ? cur[threadIdx.x - o] : 0;
        __syncthreads(); cur[threadIdx.x] += t; __syncthreads();
    }
    int excl = cur[threadIdx.x] - v;
    int node = b * 256 + threadIdx.x;
    if (node < n) {
        rowptr[(size_t)s * n + node] = base0 + excl;
        deg[(size_t)s * n + node] = v;
    }
    __syncthreads();
    cur[threadIdx.x] = excl;
    __syncthreads();
    int* colp = col + (size_t)s * nE + base0;
    for (int i = threadIdx.x; i < ecnt; i += 256) {
        unsigned int pr = pp[i];
        int r = atomicAdd(&cur[(pr >> 16) & 255], 1);
        colp[r] = (int)(pr & 0xffffu);
    }
}

// ================= MFMA Q/K/V projection (both hops; f16 outputs) ==============
static __device__ __forceinline__ short8 pack8(const float* p) {
    float4 a = *(const float4*)p;
    float4 b = *(const float4*)(p + 4);
    short8 v;
    v[0] = (short)f2bf(a.x); v[1] = (short)f2bf(a.y);
    v[2] = (short)f2bf(a.z); v[3] = (short)f2bf(a.w);
    v[4] = (short)f2bf(b.x); v[5] = (short)f2bf(b.y);
    v[6] = (short)f2bf(b.z); v[7] = (short)f2bf(b.w);
    return v;
}

template<int NT, int A>
__device__ __forceinline__ void mat_mfma_h(
    const short8* xf, const unsigned short* W, const float* b,
    unsigned short* o, int node0, int r, int kg)
{
    floatx4 acc[NT];
#pragma unroll
    for (int nt = 0; nt < NT; ++nt) {
        float bb = b[nt * 16 + r];
        acc[nt] = (floatx4){bb, bb, bb, bb};
    }
#pragma unroll
    for (int ks = 0; ks < 4; ++ks) {
#pragma unroll
        for (int nt = 0; nt < NT; ++nt) {
            short8 wf = *(const short8*)((const short*)W + (size_t)(nt * 16 + r) * IN_F + ks * 32 + kg * 8);
            acc[nt] = __builtin_amdgcn_mfma_f32_16x16x32_bf16(xf[ks], wf, acc[nt], 0, 0, 0);
        }
    }
#pragma unroll
    for (int nt = 0; nt < NT; ++nt)
#pragma unroll
        for (int reg = 0; reg < 4; ++reg)
            o[(size_t)(node0 + kg * 4 + reg) * A + nt * 16 + r] = f2h(acc[nt][reg]);
}

template<int A>
__global__ __launch_bounds__(256) void qkv2_mfma(
    const float* __restrict__ x,
    const unsigned short* __restrict__ Wq, const float* __restrict__ bq,
    const unsigned short* __restrict__ Wk, const float* __restrict__ bk,
    const unsigned short* __restrict__ Wv, const float* __restrict__ bv,
    unsigned short* __restrict__ q0, unsigned short* __restrict__ q1,
    unsigned short* __restrict__ k0, unsigned short* __restrict__ k1,
    unsigned short* __restrict__ v0, unsigned short* __restrict__ v1,
    int n)
{
    constexpr int NT = A / 16;
    const int wave = threadIdx.x >> 6;
    const int lane = threadIdx.x & 63;
    const int node0 = blockIdx.x * 64 + wave * 16;
    if (node0 >= n) return;
    const int r  = lane & 15;
    const int kg = lane >> 4;

    short8 xf[4];
    const float* xr = x + (size_t)(node0 + r) * IN_F + kg * 8;
#pragma unroll
    for (int ks = 0; ks < 4; ++ks) xf[ks] = pack8(xr + ks * 32);

    mat_mfma_h<NT, A>(xf, Wq,                    bq,     q0, node0, r, kg);
    mat_mfma_h<NT, A>(xf, Wk,                    bk,     k0, node0, r, kg);
    mat_mfma_h<NT, A>(xf, Wv,                    bv,     v0, node0, r, kg);
    mat_mfma_h<NT, A>(xf, Wq + (size_t)A * IN_F, bq + A, q1, node0, r, kg);
    mat_mfma_h<NT, A>(xf, Wk + (size_t)A * IN_F, bk + A, k1, node0, r, kg);
    mat_mfma_h<NT, A>(xf, Wv + (size_t)A * IN_F, bv + A, v1, node0, r, kg);
}

// ================= fused per-node gather phases (all-f16 payload) ==============
// layer-0 phase: eslot = lane>>4 (4 eslots, 2x unroll = 8 edges in flight/wave),
// il = lane&15 covers 8 contiguous elems; head-group = 4 lanes (shfl 1,2).
__device__ __forceinline__ void gat_phase128(
    const unsigned short* __restrict__ q, const uint4* __restrict__ kb,
    const uint4* __restrict__ vb,
    const int* __restrict__ rowptr, const int* __restrict__ deg,
    const int* __restrict__ col,
    int wid, int eslot, int il, float scale, float* r)
{
    uint4 qw = *(const uint4*)(q + (size_t)wid * 128 + il * 8);
    int start = rowptr[wid], cnt = deg[wid];
    float l = 0.f;
    h2 ax2[4];
#pragma unroll
    for (int j = 0; j < 4; ++j) ax2[j] = (h2){(_Float16)0.f, (_Float16)0.f};

    int t = eslot;
    for (; t + 4 < cnt; t += 8) {
        int d0 = col[start + t], d1 = col[start + t + 4];
        uint4 kw0 = kb[(size_t)d0 * 16 + il];
        uint4 kw1 = kb[(size_t)d1 * 16 + il];
        uint4 vw0 = vb[(size_t)d0 * 16 + il];
        uint4 vw1 = vb[(size_t)d1 * 16 + il];
        float p0 = dot8h(qw, kw0);
        float p1 = dot8h(qw, kw1);
        p0 += __shfl_xor(p0, 1); p0 += __shfl_xor(p0, 2);
        p1 += __shfl_xor(p1, 1); p1 += __shfl_xor(p1, 2);
        float e0 = __expf(p0 * scale);
        float e1 = __expf(p1 * scale);
        l += e0 + e1;
        _Float16 h0 = (_Float16)e0, h1 = (_Float16)e1;
        h2 e02 = (h2){h0, h0}, e12 = (h2){h1, h1};
        ax2[0] += e02 * uh2(vw0.x); ax2[1] += e02 * uh2(vw0.y);
        ax2[2] += e02 * uh2(vw0.z); ax2[3] += e02 * uh2(vw0.w);
        ax2[0] += e12 * uh2(vw1.x); ax2[1] += e12 * uh2(vw1.y);
        ax2[2] += e12 * uh2(vw1.z); ax2[3] += e12 * uh2(vw1.w);
    }
    for (; t < cnt; t += 4) {
        int d = col[start + t];
        uint4 kw = kb[(size_t)d * 16 + il];
        uint4 vw = vb[(size_t)d * 16 + il];
        float p = dot8h(qw, kw);
        p += __shfl_xor(p, 1); p += __shfl_xor(p, 2);
        float e = __expf(p * scale);
        l += e;
        _Float16 h = (_Float16)e;
        h2 e2 = (h2){h, h};
        ax2[0] += e2 * uh2(vw.x); ax2[1] += e2 * uh2(vw.y);
        ax2[2] += e2 * uh2(vw.z); ax2[3] += e2 * uh2(vw.w);
    }
    float ax[8];
#pragma unroll
    for (int j = 0; j < 4; ++j) { ax[2 * j] = (float)ax2[j].x; ax[2 * j + 1] = (float)ax2[j].y; }
#pragma unroll
    for (int off = 16; off <= 32; off <<= 1) {
        l += __shfl_xor(l, off);
#pragma unroll
        for (int j = 0; j < 8; ++j) ax[j] += __shfl_xor(ax[j], off);
    }
    float inv = (l > 0.f) ? 1.f / l : 0.f;
#pragma unroll
    for (int j = 0; j < 8; ++j) r[j] = ax[j] * inv;
}

// both layer-0 hops; ELU'd sum written once (f32 node-major for layer-1 input)
__global__ __launch_bounds__(256) void gat2_128(
    const unsigned short* __restrict__ q0, const unsigned short* __restrict__ q1,
    const uint4* __restrict__ k0, const uint4* __restrict__ v0,
    const uint4* __restrict__ k1, const uint4* __restrict__ v1,
    const int* __restrict__ rp0, const int* __restrict__ dg0, const int* __restrict__ cl0,
    const int* __restrict__ rp1, const int* __restrict__ dg1, const int* __restrict__ cl1,
    float* __restrict__ out, float scale, int n)
{
    int wid  = (blockIdx.x * 256 + threadIdx.x) >> 6;
    int lane = threadIdx.x & 63;
    if (wid >= n) return;
    int eslot = lane >> 4, il = lane & 15;

    float r0[8], r1[8];
    gat_phase128(q0, k0, v0, rp0, dg0, cl0, wid, eslot, il, scale, r0);
    gat_phase128(q1, k1, v1, rp1, dg1, cl1, wid, eslot, il, scale, r1);

    if (eslot == 0) {
        float z[8];
#pragma unroll
        for (int j = 0; j < 8; ++j) z[j] = elu1(r0[j] + 0.5f * r1[j]);
        float4* op = (float4*)(out + (size_t)wid * 128 + il * 8);
        op[0] = make_float4(z[0], z[1], z[2], z[3]);
        op[1] = make_float4(z[4], z[5], z[6], z[7]);
    }
}

// layer-1 phase: eslot = lane>>2 (16 edges in flight), il = lane&3 = head (in-lane dot)
__device__ __forceinline__ void gat_phase32(
    const unsigned short* __restrict__ q, const uint4* __restrict__ kb,
    const uint4* __restrict__ vb,
    const int* __restrict__ rowptr, const int* __restrict__ deg,
    const int* __restrict__ col,
    int wid, int eslot, int il, float scale, float* r)
{
    uint4 qw = *(const uint4*)(q + (size_t)wid * 32 + il * 8);
    int start = rowptr[wid], cnt = deg[wid];
    float l = 0.f;
    h2 ax2[4];
#pragma unroll
    for (int j = 0; j < 4; ++j) ax2[j] = (h2){(_Float16)0.f, (_Float16)0.f};

    for (int t = eslot; t < cnt; t += 16) {
        int d = col[start + t];
        uint4 kw = kb[(size_t)d * 4 + il];
        uint4 vw = vb[(size_t)d * 4 + il];
        float p = dot8h(qw, kw);
        float e = __expf(p * scale);
        l += e;
        _Float16 h = (_Float16)e;
        h2 e2 = (h2){h, h};
        ax2[0] += e2 * uh2(vw.x); ax2[1] += e2 * uh2(vw.y);
        ax2[2] += e2 * uh2(vw.z); ax2[3] += e2 * uh2(vw.w);
    }
    float ax[8];
#pragma unroll
    for (int j = 0; j < 4; ++j) { ax[2 * j] = (float)ax2[j].x; ax[2 * j + 1] = (float)ax2[j].y; }
#pragma unroll
    for (int off = 4; off <= 32; off <<= 1) {
        l += __shfl_xor(l, off);
#pragma unroll
        for (int j = 0; j < 8; ++j) ax[j] += __shfl_xor(ax[j], off);
    }
    float inv = (l > 0.f) ? 1.f / l : 0.f;
#pragma unroll
    for (int j = 0; j < 8; ++j) r[j] = ax[j] * inv;
}

// both layer-1 hops + fused log_softmax -> final output
__global__ __launch_bounds__(256) void gat2_32(
    const unsigned short* __restrict__ q0, const unsigned short* __restrict__ q1,
    const uint4* __restrict__ k0, const uint4* __restrict__ v0,
    const uint4* __restrict__ k1, const uint4* __restrict__ v1,
    const int* __restrict__ rp0, const int* __restrict__ dg0, const int* __restrict__ cl0,
    const int* __restrict__ rp1, const int* __restrict__ dg1, const int* __restrict__ cl1,
    float* __restrict__ outp, float scale, int n)
{
    int wid  = (blockIdx.x * 256 + threadIdx.x) >> 6;
    int lane = threadIdx.x & 63;
    if (wid >= n) return;
    int eslot = lane >> 2, il = lane & 3;

    float r0[8], r1[8];
    gat_phase32(q0, k0, v0, rp0, dg0, cl0, wid, eslot, il, scale, r0);
    gat_phase32(q1, k1, v1, rp1, dg1, cl1, wid, eslot, il, scale, r1);

    if (eslot == 0) {
        float z[8];
#pragma unroll
        for (int j = 0; j < 8; ++j) z[j] = r0[j] + 0.5f * r1[j];
        float mx = z[0];
#pragma unroll
        for (int j = 1; j < 8; ++j) mx = fmaxf(mx, z[j]);
        mx = fmaxf(mx, __shfl_xor(mx, 1));
        mx = fmaxf(mx, __shfl_xor(mx, 2));
        float sm = 0.f;
#pragma unroll
        for (int j = 0; j < 8; ++j) sm += __expf(z[j] - mx);
        sm += __shfl_xor(sm, 1);
        sm += __shfl_xor(sm, 2);
        float lse = mx + logf(sm);
        float4* op = (float4*)(outp + (size_t)wid * 32 + il * 8);
        op[0] = make_float4(z[0] - lse, z[1] - lse, z[2] - lse, z[3] - lse);
        op[1] = make_float4(z[4] - lse, z[5] - lse, z[6] - lse, z[7] - lse);
    }
}

extern "C" void kernel_launch(void* const* d_in, const int* in_sizes, int n_in,
                              void* d_out, int out_size, void* d_ws, size_t ws_size,
                              hipStream_t stream)
{
    const float* x   = (const float*)d_in[0];
    const float* Wq0 = (const float*)d_in[1];
    const float* bq0 = (const float*)d_in[2];
    const float* Wk0 = (const float*)d_in[3];
    const float* bk0 = (const float*)d_in[4];
    const float* Wv0 = (const float*)d_in[5];
    const float* bv0 = (const float*)d_in[6];
    const float* Wq1 = (const float*)d_in[7];
    const float* bq1 = (const float*)d_in[8];
    const float* Wk1 = (const float*)d_in[9];
    const float* bk1 = (const float*)d_in[10];
    const float* Wv1 = (const float*)d_in[11];
    const float* bv1 = (const float*)d_in[12];
    const int* e0 = (const int*)d_in[13];
    const int* e1 = (const int*)d_in[14];
    const int* e2 = (const int*)d_in[15];
    const int* e3 = (const int*)d_in[16];

    char* w = (char*)d_ws;
    unsigned short* q0h = (unsigned short*)w; w += (size_t)N_NODES * HID * 2;   // 12.8 MB
    unsigned short* q1h = (unsigned short*)w; w += (size_t)N_NODES * HID * 2;
    unsigned short* k0b = (unsigned short*)w; w += (size_t)N_NODES * HID * 2;
    unsigned short* v0b = (unsigned short*)w; w += (size_t)N_NODES * HID * 2;
    unsigned short* k1b = (unsigned short*)w; w += (size_t)N_NODES * HID * 2;
    unsigned short* v1b = (unsigned short*)w; w += (size_t)N_NODES * HID * 2;
    float*          acc = (float*)w;          w += (size_t)N_NODES * HID * 4;   // 25.6
    int* deg    = (int*)w; w += (size_t)4 * N_NODES * 4;
    int* rowptr = (int*)w; w += (size_t)4 * N_NODES * 4;
    int* col    = (int*)w; w += (size_t)4 * N_EDGES * 4;
    int* bcnt   = (int*)w; w += (size_t)4 * NBUCK * 4;
    int* bbase  = (int*)w; w += (size_t)4 * (NBUCK + 1) * 4;
    int* bcur   = (int*)w; w += (size_t)4 * NBUCK * 4;
    unsigned short* wq0b = (unsigned short*)w; w += (size_t)2 * HID * IN_F * 2;
    unsigned short* wk0b = (unsigned short*)w; w += (size_t)2 * HID * IN_F * 2;
    unsigned short* wv0b = (unsigned short*)w; w += (size_t)2 * HID * IN_F * 2;
    unsigned short* wq1b = (unsigned short*)w; w += (size_t)2 * CLS * IN_F * 2;
    unsigned short* wk1b = (unsigned short*)w; w += (size_t)2 * CLS * IN_F * 2;
    unsigned short* wv1b = (unsigned short*)w; w += (size_t)2 * CLS * IN_F * 2;

    // aliases: pairs (12.8 MB) lives in q0h during CSR build (before any qkv).
    unsigned int* pairs = (unsigned int*)q0h;
    // layer-1 f16 buffers (3.2 MB each) alias layer-0 q buffers (dead after gat2_128)
    unsigned short* qA0 = q0h;
    unsigned short* qA1 = q0h + (size_t)N_NODES * CLS;
    unsigned short* kA0 = q1h;
    unsigned short* vA0 = q1h + (size_t)N_NODES * CLS;
    unsigned short* kA1 = k0b;
    unsigned short* vA1 = k0b + (size_t)N_NODES * CLS;

    float* out = (float*)d_out;
    const int NB = (N_NODES + 3) / 4;
    const int QB = (N_NODES / 16 + 3) / 4;
    const float sc0 = 1.f / sqrtf(32.f), sc1 = 1.f / sqrtf(8.f);

    // ---------- weights -> bf16 (1 launch) ----------
    const int W0 = 2 * HID * IN_F, W1 = 2 * CLS * IN_F;
    conv6<<<dim3((W0 + 255) / 256, 6), 256, 0, stream>>>(
        Wq0, Wk0, Wv0, Wq1, Wk1, Wv1, wq0b, wk0b, wv0b, wq1b, wk1b, wv1b, W0, W1);

    // ---------- build 4 CSRs ----------
    hipMemsetAsync(bcnt, 0, (size_t)4 * NBUCK * 4, stream);
    bucket_hist<<<dim3(256, 4), 256, 0, stream>>>(e0, e1, e2, e3, bcnt, N_EDGES);
    bucket_scan<<<4, 256, 0, stream>>>(bcnt, bbase, bcur);
    pass1_scatter<<<dim3((N_EDGES + TILE - 1) / TILE, 4), 256, 0, stream>>>(
        e0, e1, e2, e3, bcur, pairs, N_EDGES);
    pass2_place<<<dim3(NBUCK, 4), 256, 0, stream>>>(
        pairs, bbase, rowptr, deg, col, N_EDGES, N_NODES);

    // ================= layer 0: qkv both hops, gather both hops =================
    qkv2_mfma<HID><<<QB, 256, 0, stream>>>(
        x, wq0b, bq0, wk0b, bk0, wv0b, bv0,
        q0h, q1h, k0b, k1b, v0b, v1b, N_NODES);
    gat2_128<<<NB, 256, 0, stream>>>(
        q0h, q1h,
        (const uint4*)k0b, (const uint4*)v0b, (const uint4*)k1b, (const uint4*)v1b,
        rowptr,            deg,            col,
        rowptr + N_NODES,  deg + N_NODES,  col + N_EDGES,
        acc, sc0, N_NODES);

    // ================= layer 1: qkv both hops, gather + logsoftmax ==============
    qkv2_mfma<CLS><<<QB, 256, 0, stream>>>(
        acc, wq1b, bq1, wk1b, bk1, wv1b, bv1,
        qA0, qA1, kA0, kA1, vA0, vA1, N_NODES);
    gat2_32<<<NB, 256, 0, stream>>>(
        qA0, qA1,
        (const uint4*)kA0, (const uint4*)vA0, (const uint4*)kA1, (const uint4*)vA1,
        rowptr + 2 * N_NODES, deg + 2 * N_NODES, col + (size_t)2 * N_EDGES,
        rowptr + 3 * N_NODES, deg + 3 * N_NODES, col + (size_t)3 * N_EDGES,
        out, sc1, N_NODES);
}

// Round 10
// 352.474 us; speedup vs baseline: 1.7781x; 1.0793x over previous
//
#include <hip/hip_runtime.h>
#include <hip/hip_bf16.h>
#include <math.h>

#define N_NODES 50000
#define N_EDGES 800000
#define IN_F    128
#define HID     128
#define CLS     32
#define NHEAD   4
#define NBUCK   196        // ceil(N_NODES / 256)

typedef __attribute__((ext_vector_type(8))) short  short8;
typedef __attribute__((ext_vector_type(4))) float  floatx4;
typedef __attribute__((ext_vector_type(2))) float  f32x2;
typedef _Float16 h2 __attribute__((ext_vector_type(2)));

// ---------- conversions ----------
static __device__ __forceinline__ unsigned short f2bf(float f) {
    unsigned int u = __float_as_uint(f);
    return (unsigned short)((u + 0x7fffu + ((u >> 16) & 1u)) >> 16);
}
static __device__ __forceinline__ unsigned short f2h(float f) {
    return __builtin_bit_cast(unsigned short, (_Float16)f);
}
static __device__ __forceinline__ h2 uh2(unsigned int u) {
    return __builtin_bit_cast(h2, u);
}
static __device__ __forceinline__ unsigned char f2fp8(float f) {
    unsigned int p = (unsigned int)__builtin_amdgcn_cvt_pk_fp8_f32(f, f, 0, false);
    return (unsigned char)(p & 0xffu);
}
static __device__ __forceinline__ float elu1(float x) {
    return x > 0.f ? x : expm1f(x);
}

// packed-f16 8-elem dot (layer-1): 4 pk_fma + f32 fold
static __device__ __forceinline__ float dot8h(uint4 qw, uint4 kw) {
    h2 d = uh2(qw.x) * uh2(kw.x);
    d += uh2(qw.y) * uh2(kw.y);
    d += uh2(qw.z) * uh2(kw.z);
    d += uh2(qw.w) * uh2(kw.w);
    return (float)d.x + (float)d.y;
}

// fp8 8-elem dot against f32 q (layer-0)
static __device__ __forceinline__ float dot8f8(const float* qf, uint2 kw) {
    f32x2 a0 = __builtin_amdgcn_cvt_pk_f32_fp8((int)kw.x, false);
    f32x2 a1 = __builtin_amdgcn_cvt_pk_f32_fp8((int)kw.x, true);
    f32x2 a2 = __builtin_amdgcn_cvt_pk_f32_fp8((int)kw.y, false);
    f32x2 a3 = __builtin_amdgcn_cvt_pk_f32_fp8((int)kw.y, true);
    return fmaf(qf[0], a0.x, fmaf(qf[1], a0.y, fmaf(qf[2], a1.x, fmaf(qf[3], a1.y,
           fmaf(qf[4], a2.x, fmaf(qf[5], a2.y, fmaf(qf[6], a3.x, qf[7] * a3.y)))))));
}
static __device__ __forceinline__ void acc8f8(float* ax, float e, uint2 vw) {
    f32x2 a0 = __builtin_amdgcn_cvt_pk_f32_fp8((int)vw.x, false);
    f32x2 a1 = __builtin_amdgcn_cvt_pk_f32_fp8((int)vw.x, true);
    f32x2 a2 = __builtin_amdgcn_cvt_pk_f32_fp8((int)vw.y, false);
    f32x2 a3 = __builtin_amdgcn_cvt_pk_f32_fp8((int)vw.y, true);
    ax[0] = fmaf(e, a0.x, ax[0]); ax[1] = fmaf(e, a0.y, ax[1]);
    ax[2] = fmaf(e, a1.x, ax[2]); ax[3] = fmaf(e, a1.y, ax[3]);
    ax[4] = fmaf(e, a2.x, ax[4]); ax[5] = fmaf(e, a2.y, ax[5]);
    ax[6] = fmaf(e, a3.x, ax[6]); ax[7] = fmaf(e, a3.y, ax[7]);
}

// ---------- weight conversion: all 6 matrices in one launch ----------
__global__ __launch_bounds__(256) void conv6(
    const float* __restrict__ a0, const float* __restrict__ a1, const float* __restrict__ a2,
    const float* __restrict__ a3, const float* __restrict__ a4, const float* __restrict__ a5,
    unsigned short* __restrict__ o0, unsigned short* __restrict__ o1, unsigned short* __restrict__ o2,
    unsigned short* __restrict__ o3, unsigned short* __restrict__ o4, unsigned short* __restrict__ o5,
    int cBig, int cSmall)
{
    const float* srcs[6] = {a0, a1, a2, a3, a4, a5};
    unsigned short* dsts[6] = {o0, o1, o2, o3, o4, o5};
    int s = blockIdx.y;
    int count = (s < 3) ? cBig : cSmall;
    int i = blockIdx.x * 256 + threadIdx.x;
    if (i < count) dsts[s][i] = f2bf(srcs[s][i]);
}

// ================= CSR build: 2-pass coarse-bucket counting sort =================
__global__ __launch_bounds__(256) void bucket_hist(
    const int* __restrict__ e0, const int* __restrict__ e1,
    const int* __restrict__ e2, const int* __restrict__ e3,
    int* __restrict__ bcnt, int nE)
{
    const int s = blockIdx.y;
    const int* ep = (s == 0) ? e0 : (s == 1) ? e1 : (s == 2) ? e2 : e3;
    __shared__ int h[NBUCK];
    for (int i = threadIdx.x; i < NBUCK; i += 256) h[i] = 0;
    __syncthreads();
    for (int e = blockIdx.x * 256 + threadIdx.x; e < nE; e += gridDim.x * 256)
        atomicAdd(&h[ep[e] >> 8], 1);
    __syncthreads();
    for (int i = threadIdx.x; i < NBUCK; i += 256)
        if (h[i]) atomicAdd(&bcnt[s * NBUCK + i], h[i]);
}

__global__ __launch_bounds__(256) void bucket_scan(
    const int* __restrict__ bcnt, int* __restrict__ bbase, int* __restrict__ bcur)
{
    int s = blockIdx.x;
    __shared__ int tmp[256];
    int v = (threadIdx.x < NBUCK) ? bcnt[s * NBUCK + threadIdx.x] : 0;
    tmp[threadIdx.x] = v; __syncthreads();
    for (int o = 1; o < 256; o <<= 1) {
        int t = (threadIdx.x >= o) ? tmp[threadIdx.x - o] : 0;
        __syncthreads(); tmp[threadIdx.x] += t; __syncthreads();
    }
    int excl = tmp[threadIdx.x] - v;
    if (threadIdx.x < NBUCK) {
        bbase[s * (NBUCK + 1) + threadIdx.x] = excl;
        bcur[s * NBUCK + threadIdx.x] = excl;
    }
    if (threadIdx.x == NBUCK - 1)
        bbase[s * (NBUCK + 1) + NBUCK] = excl + v;
}

// pass 1: packed (src&255)<<16 | dst  (dst < 65536 since N=50000)
#define TILE 8192
__global__ __launch_bounds__(256) void pass1_scatter(
    const int* __restrict__ e0, const int* __restrict__ e1,
    const int* __restrict__ e2, const int* __restrict__ e3,
    int* __restrict__ bcur, unsigned int* __restrict__ pairs, int nE)
{
    const int s = blockIdx.y;
    const int* ep = (s == 0) ? e0 : (s == 1) ? e1 : (s == 2) ? e2 : e3;
    const int tile0 = blockIdx.x * TILE;
    __shared__ int hist[NBUCK], base[NBUCK], cur[NBUCK];
    for (int i = threadIdx.x; i < NBUCK; i += 256) { hist[i] = 0; cur[i] = 0; }
    __syncthreads();
    for (int i = threadIdx.x; i < TILE; i += 256) {
        int e = tile0 + i;
        if (e < nE) atomicAdd(&hist[ep[e] >> 8], 1);
    }
    __syncthreads();
    for (int i = threadIdx.x; i < NBUCK; i += 256)
        base[i] = hist[i] ? atomicAdd(&bcur[s * NBUCK + i], hist[i]) : 0;
    __syncthreads();
    unsigned int* pp = pairs + (size_t)s * nE;
    for (int i = threadIdx.x; i < TILE; i += 256) {
        int e = tile0 + i;
        if (e < nE) {
            int src = ep[e], dst = ep[e + nE];
            int b = src >> 8;
            int r = atomicAdd(&cur[b], 1);
            pp[base[b] + r] = ((unsigned int)(src & 255) << 16) | (unsigned int)dst;
        }
    }
}

__global__ __launch_bounds__(256) void pass2_place(
    const unsigned int* __restrict__ pairs, const int* __restrict__ bbase,
    int* __restrict__ rowptr, int* __restrict__ deg, int* __restrict__ col,
    int nE, int n)
{
    const int s = blockIdx.y, b = blockIdx.x;
    const int base0 = bbase[s * (NBUCK + 1) + b];
    const int ecnt  = bbase[s * (NBUCK + 1) + b + 1] - base0;
    const unsigned int* pp = pairs + (size_t)s * nE + base0;
    __shared__ int hist[256], cur[256];
    hist[threadIdx.x] = 0;
    __syncthreads();
    for (int i = threadIdx.x; i < ecnt; i += 256)
        atomicAdd(&hist[(pp[i] >> 16) & 255], 1);
    __syncthreads();
    int v = hist[threadIdx.x];
    cur[threadIdx.x] = v; __syncthreads();
    for (int o = 1; o < 256; o <<= 1) {
        int t = (threadIdx.x >= o) ? cur[threadIdx.x - o] : 0;
        __syncthreads(); cur[threadIdx.x] += t; __syncthreads();
    }
    int excl = cur[threadIdx.x] - v;
    int node = b * 256 + threadIdx.x;
    if (node < n) {
        rowptr[(size_t)s * n + node] = base0 + excl;
        deg[(size_t)s * n + node] = v;
    }
    __syncthreads();
    cur[threadIdx.x] = excl;
    __syncthreads();
    int* colp = col + (size_t)s * nE + base0;
    for (int i = threadIdx.x; i < ecnt; i += 256) {
        unsigned int pr = pp[i];
        int r = atomicAdd(&cur[(pr >> 16) & 255], 1);
        colp[r] = (int)(pr & 0xffffu);
    }
}

// ================= MFMA Q/K/V projection (both hops) ===========================
static __device__ __forceinline__ short8 pack8(const float* p) {
    float4 a = *(const float4*)p;
    float4 b = *(const float4*)(p + 4);
    short8 v;
    v[0] = (short)f2bf(a.x); v[1] = (short)f2bf(a.y);
    v[2] = (short)f2bf(a.z); v[3] = (short)f2bf(a.w);
    v[4] = (short)f2bf(b.x); v[5] = (short)f2bf(b.y);
    v[6] = (short)f2bf(b.z); v[7] = (short)f2bf(b.w);
    return v;
}

// MODE: 0 = f16 out (2B), 1 = fp8 e4m3 out (1B)
template<int NT, int A, int MODE>
__device__ __forceinline__ void mat_mfma_o(
    const short8* xf, const unsigned short* W, const float* b,
    void* o, int node0, int r, int kg)
{
    floatx4 acc[NT];
#pragma unroll
    for (int nt = 0; nt < NT; ++nt) {
        float bb = b[nt * 16 + r];
        acc[nt] = (floatx4){bb, bb, bb, bb};
    }
#pragma unroll
    for (int ks = 0; ks < 4; ++ks) {
#pragma unroll
        for (int nt = 0; nt < NT; ++nt) {
            short8 wf = *(const short8*)((const short*)W + (size_t)(nt * 16 + r) * IN_F + ks * 32 + kg * 8);
            acc[nt] = __builtin_amdgcn_mfma_f32_16x16x32_bf16(xf[ks], wf, acc[nt], 0, 0, 0);
        }
    }
#pragma unroll
    for (int nt = 0; nt < NT; ++nt)
#pragma unroll
        for (int reg = 0; reg < 4; ++reg) {
            size_t idx = (size_t)(node0 + kg * 4 + reg) * A + nt * 16 + r;
            if constexpr (MODE == 0) ((unsigned short*)o)[idx] = f2h(acc[nt][reg]);
            else                     ((unsigned char*)o)[idx]  = f2fp8(acc[nt][reg]);
        }
}

// KV8: layer-0 stores k/v as fp8; q always f16
template<int A, bool KV8>
__global__ __launch_bounds__(256) void qkv2_mfma(
    const float* __restrict__ x,
    const unsigned short* __restrict__ Wq, const float* __restrict__ bq,
    const unsigned short* __restrict__ Wk, const float* __restrict__ bk,
    const unsigned short* __restrict__ Wv, const float* __restrict__ bv,
    unsigned short* __restrict__ q0, unsigned short* __restrict__ q1,
    void* __restrict__ k0, void* __restrict__ k1,
    void* __restrict__ v0, void* __restrict__ v1,
    int n)
{
    constexpr int NT = A / 16;
    constexpr int KVM = KV8 ? 1 : 0;
    const int wave = threadIdx.x >> 6;
    const int lane = threadIdx.x & 63;
    const int node0 = blockIdx.x * 64 + wave * 16;
    if (node0 >= n) return;
    const int r  = lane & 15;
    const int kg = lane >> 4;

    short8 xf[4];
    const float* xr = x + (size_t)(node0 + r) * IN_F + kg * 8;
#pragma unroll
    for (int ks = 0; ks < 4; ++ks) xf[ks] = pack8(xr + ks * 32);

    mat_mfma_o<NT, A, 0  >(xf, Wq,                    bq,     q0, node0, r, kg);
    mat_mfma_o<NT, A, KVM>(xf, Wk,                    bk,     k0, node0, r, kg);
    mat_mfma_o<NT, A, KVM>(xf, Wv,                    bv,     v0, node0, r, kg);
    mat_mfma_o<NT, A, 0  >(xf, Wq + (size_t)A * IN_F, bq + A, q1, node0, r, kg);
    mat_mfma_o<NT, A, KVM>(xf, Wk + (size_t)A * IN_F, bk + A, k1, node0, r, kg);
    mat_mfma_o<NT, A, KVM>(xf, Wv + (size_t)A * IN_F, bv + A, v1, node0, r, kg);
}

// ================= layer-0 gather phase: fp8 k/v, f16 q ========================
// eslot = lane>>4 (4 eslots, 2x unroll = 8 edges in flight/wave),
// il = lane&15 covers 8 contiguous elems (uint2 = 8 B); head-group = 4 lanes.
__device__ __forceinline__ void gat_phase128(
    const unsigned short* __restrict__ q, const uint2* __restrict__ kb,
    const uint2* __restrict__ vb,
    const int* __restrict__ rowptr, const int* __restrict__ deg,
    const int* __restrict__ col,
    int wid, int eslot, int il, float scale, float* r)
{
    uint4 qw = *(const uint4*)(q + (size_t)wid * 128 + il * 8);
    float qf[8];
    {
        h2 t0 = uh2(qw.x), t1 = uh2(qw.y), t2 = uh2(qw.z), t3 = uh2(qw.w);
        qf[0] = (float)t0.x; qf[1] = (float)t0.y;
        qf[2] = (float)t1.x; qf[3] = (float)t1.y;
        qf[4] = (float)t2.x; qf[5] = (float)t2.y;
        qf[6] = (float)t3.x; qf[7] = (float)t3.y;
    }
    int start = rowptr[wid], cnt = deg[wid];
    float l = 0.f;
    float ax[8];
#pragma unroll
    for (int j = 0; j < 8; ++j) ax[j] = 0.f;

    int t = eslot;
    for (; t + 4 < cnt; t += 8) {
        int d0 = col[start + t], d1 = col[start + t + 4];
        uint2 kw0 = kb[(size_t)d0 * 16 + il];
        uint2 kw1 = kb[(size_t)d1 * 16 + il];
        uint2 vw0 = vb[(size_t)d0 * 16 + il];
        uint2 vw1 = vb[(size_t)d1 * 16 + il];
        float p0 = dot8f8(qf, kw0);
        float p1 = dot8f8(qf, kw1);
        p0 += __shfl_xor(p0, 1); p0 += __shfl_xor(p0, 2);
        p1 += __shfl_xor(p1, 1); p1 += __shfl_xor(p1, 2);
        float e0 = __expf(p0 * scale);
        float e1 = __expf(p1 * scale);
        l += e0 + e1;
        acc8f8(ax, e0, vw0);
        acc8f8(ax, e1, vw1);
    }
    for (; t < cnt; t += 4) {
        int d = col[start + t];
        uint2 kw = kb[(size_t)d * 16 + il];
        uint2 vw = vb[(size_t)d * 16 + il];
        float p = dot8f8(qf, kw);
        p += __shfl_xor(p, 1); p += __shfl_xor(p, 2);
        float e = __expf(p * scale);
        l += e;
        acc8f8(ax, e, vw);
    }
#pragma unroll
    for (int off = 16; off <= 32; off <<= 1) {
        l += __shfl_xor(l, off);
#pragma unroll
        for (int j = 0; j < 8; ++j) ax[j] += __shfl_xor(ax[j], off);
    }
    float inv = (l > 0.f) ? 1.f / l : 0.f;
#pragma unroll
    for (int j = 0; j < 8; ++j) r[j] = ax[j] * inv;
}

// both layer-0 hops; ELU'd sum written once (f32 node-major for layer-1 input)
__global__ __launch_bounds__(256) void gat2_128(
    const unsigned short* __restrict__ q0, const unsigned short* __restrict__ q1,
    const uint2* __restrict__ k0, const uint2* __restrict__ v0,
    const uint2* __restrict__ k1, const uint2* __restrict__ v1,
    const int* __restrict__ rp0, const int* __restrict__ dg0, const int* __restrict__ cl0,
    const int* __restrict__ rp1, const int* __restrict__ dg1, const int* __restrict__ cl1,
    float* __restrict__ out, float scale, int n)
{
    int wid  = (blockIdx.x * 256 + threadIdx.x) >> 6;
    int lane = threadIdx.x & 63;
    if (wid >= n) return;
    int eslot = lane >> 4, il = lane & 15;

    float r0[8], r1[8];
    gat_phase128(q0, k0, v0, rp0, dg0, cl0, wid, eslot, il, scale, r0);
    gat_phase128(q1, k1, v1, rp1, dg1, cl1, wid, eslot, il, scale, r1);

    if (eslot == 0) {
        float z[8];
#pragma unroll
        for (int j = 0; j < 8; ++j) z[j] = elu1(r0[j] + 0.5f * r1[j]);
        float4* op = (float4*)(out + (size_t)wid * 128 + il * 8);
        op[0] = make_float4(z[0], z[1], z[2], z[3]);
        op[1] = make_float4(z[4], z[5], z[6], z[7]);
    }
}

// ================= layer-1 gather phase (f16 payload) ==========================
// eslot = lane>>2 (16 edges in flight), il = lane&3 = head (in-lane dot)
__device__ __forceinline__ void gat_phase32(
    const unsigned short* __restrict__ q, const uint4* __restrict__ kb,
    const uint4* __restrict__ vb,
    const int* __restrict__ rowptr, const int* __restrict__ deg,
    const int* __restrict__ col,
    int wid, int eslot, int il, float scale, float* r)
{
    uint4 qw = *(const uint4*)(q + (size_t)wid * 32 + il * 8);
    int start = rowptr[wid], cnt = deg[wid];
    float l = 0.f;
    h2 ax2[4];
#pragma unroll
    for (int j = 0; j < 4; ++j) ax2[j] = (h2){(_Float16)0.f, (_Float16)0.f};

    for (int t = eslot; t < cnt; t += 16) {
        int d = col[start + t];
        uint4 kw = kb[(size_t)d * 4 + il];
        uint4 vw = vb[(size_t)d * 4 + il];
        float p = dot8h(qw, kw);
        float e = __expf(p * scale);
        l += e;
        _Float16 h = (_Float16)e;
        h2 e2 = (h2){h, h};
        ax2[0] += e2 * uh2(vw.x); ax2[1] += e2 * uh2(vw.y);
        ax2[2] += e2 * uh2(vw.z); ax2[3] += e2 * uh2(vw.w);
    }
    float ax[8];
#pragma unroll
    for (int j = 0; j < 4; ++j) { ax[2 * j] = (float)ax2[j].x; ax[2 * j + 1] = (float)ax2[j].y; }
#pragma unroll
    for (int off = 4; off <= 32; off <<= 1) {
        l += __shfl_xor(l, off);
#pragma unroll
        for (int j = 0; j < 8; ++j) ax[j] += __shfl_xor(ax[j], off);
    }
    float inv = (l > 0.f) ? 1.f / l : 0.f;
#pragma unroll
    for (int j = 0; j < 8; ++j) r[j] = ax[j] * inv;
}

// both layer-1 hops + fused log_softmax -> final output
__global__ __launch_bounds__(256) void gat2_32(
    const unsigned short* __restrict__ q0, const unsigned short* __restrict__ q1,
    const uint4* __restrict__ k0, const uint4* __restrict__ v0,
    const uint4* __restrict__ k1, const uint4* __restrict__ v1,
    const int* __restrict__ rp0, const int* __restrict__ dg0, const int* __restrict__ cl0,
    const int* __restrict__ rp1, const int* __restrict__ dg1, const int* __restrict__ cl1,
    float* __restrict__ outp, float scale, int n)
{
    int wid  = (blockIdx.x * 256 + threadIdx.x) >> 6;
    int lane = threadIdx.x & 63;
    if (wid >= n) return;
    int eslot = lane >> 2, il = lane & 3;

    float r0[8], r1[8];
    gat_phase32(q0, k0, v0, rp0, dg0, cl0, wid, eslot, il, scale, r0);
    gat_phase32(q1, k1, v1, rp1, dg1, cl1, wid, eslot, il, scale, r1);

    if (eslot == 0) {
        float z[8];
#pragma unroll
        for (int j = 0; j < 8; ++j) z[j] = r0[j] + 0.5f * r1[j];
        float mx = z[0];
#pragma unroll
        for (int j = 1; j < 8; ++j) mx = fmaxf(mx, z[j]);
        mx = fmaxf(mx, __shfl_xor(mx, 1));
        mx = fmaxf(mx, __shfl_xor(mx, 2));
        float sm = 0.f;
#pragma unroll
        for (int j = 0; j < 8; ++j) sm += __expf(z[j] - mx);
        sm += __shfl_xor(sm, 1);
        sm += __shfl_xor(sm, 2);
        float lse = mx + logf(sm);
        float4* op = (float4*)(outp + (size_t)wid * 32 + il * 8);
        op[0] = make_float4(z[0] - lse, z[1] - lse, z[2] - lse, z[3] - lse);
        op[1] = make_float4(z[4] - lse, z[5] - lse, z[6] - lse, z[7] - lse);
    }
}

extern "C" void kernel_launch(void* const* d_in, const int* in_sizes, int n_in,
                              void* d_out, int out_size, void* d_ws, size_t ws_size,
                              hipStream_t stream)
{
    const float* x   = (const float*)d_in[0];
    const float* Wq0 = (const float*)d_in[1];
    const float* bq0 = (const float*)d_in[2];
    const float* Wk0 = (const float*)d_in[3];
    const float* bk0 = (const float*)d_in[4];
    const float* Wv0 = (const float*)d_in[5];
    const float* bv0 = (const float*)d_in[6];
    const float* Wq1 = (const float*)d_in[7];
    const float* bq1 = (const float*)d_in[8];
    const float* Wk1 = (const float*)d_in[9];
    const float* bk1 = (const float*)d_in[10];
    const float* Wv1 = (const float*)d_in[11];
    const float* bv1 = (const float*)d_in[12];
    const int* e0 = (const int*)d_in[13];
    const int* e1 = (const int*)d_in[14];
    const int* e2 = (const int*)d_in[15];
    const int* e3 = (const int*)d_in[16];

    char* w = (char*)d_ws;
    unsigned short* q0h = (unsigned short*)w; w += (size_t)N_NODES * HID * 2;   // 12.8 MB
    unsigned short* q1h = (unsigned short*)w; w += (size_t)N_NODES * HID * 2;   // 12.8
    unsigned char*  k0c = (unsigned char*)w;  w += (size_t)N_NODES * HID;       // 6.4
    unsigned char*  v0c = (unsigned char*)w;  w += (size_t)N_NODES * HID;
    unsigned char*  k1c = (unsigned char*)w;  w += (size_t)N_NODES * HID;
    unsigned char*  v1c = (unsigned char*)w;  w += (size_t)N_NODES * HID;
    float*          acc = (float*)w;          w += (size_t)N_NODES * HID * 4;   // 25.6
    int* deg    = (int*)w; w += (size_t)4 * N_NODES * 4;
    int* rowptr = (int*)w; w += (size_t)4 * N_NODES * 4;
    int* col    = (int*)w; w += (size_t)4 * N_EDGES * 4;
    int* bcnt   = (int*)w; w += (size_t)4 * NBUCK * 4;
    int* bbase  = (int*)w; w += (size_t)4 * (NBUCK + 1) * 4;
    int* bcur   = (int*)w; w += (size_t)4 * NBUCK * 4;
    unsigned short* wq0b = (unsigned short*)w; w += (size_t)2 * HID * IN_F * 2;
    unsigned short* wk0b = (unsigned short*)w; w += (size_t)2 * HID * IN_F * 2;
    unsigned short* wv0b = (unsigned short*)w; w += (size_t)2 * HID * IN_F * 2;
    unsigned short* wq1b = (unsigned short*)w; w += (size_t)2 * CLS * IN_F * 2;
    unsigned short* wk1b = (unsigned short*)w; w += (size_t)2 * CLS * IN_F * 2;
    unsigned short* wv1b = (unsigned short*)w; w += (size_t)2 * CLS * IN_F * 2;

    // aliases: pairs (12.8 MB) lives in q0h during CSR build (before any qkv).
    unsigned int* pairs = (unsigned int*)q0h;
    // layer-1 f16 buffers (3.2 MB each) alias q0h/q1h (dead after gat2_128)
    unsigned short* qA0 = q0h;
    unsigned short* qA1 = q0h + (size_t)N_NODES * CLS;
    unsigned short* kA0 = q0h + (size_t)2 * N_NODES * CLS;
    unsigned short* vA0 = q0h + (size_t)3 * N_NODES * CLS;
    unsigned short* kA1 = q1h;
    unsigned short* vA1 = q1h + (size_t)N_NODES * CLS;

    float* out = (float*)d_out;
    const int NB = (N_NODES + 3) / 4;
    const int QB = (N_NODES / 16 + 3) / 4;
    const float sc0 = 1.f / sqrtf(32.f), sc1 = 1.f / sqrtf(8.f);

    // ---------- weights -> bf16 (1 launch) ----------
    const int W0 = 2 * HID * IN_F, W1 = 2 * CLS * IN_F;
    conv6<<<dim3((W0 + 255) / 256, 6), 256, 0, stream>>>(
        Wq0, Wk0, Wv0, Wq1, Wk1, Wv1, wq0b, wk0b, wv0b, wq1b, wk1b, wv1b, W0, W1);

    // ---------- build 4 CSRs ----------
    hipMemsetAsync(bcnt, 0, (size_t)4 * NBUCK * 4, stream);
    bucket_hist<<<dim3(256, 4), 256, 0, stream>>>(e0, e1, e2, e3, bcnt, N_EDGES);
    bucket_scan<<<4, 256, 0, stream>>>(bcnt, bbase, bcur);
    pass1_scatter<<<dim3((N_EDGES + TILE - 1) / TILE, 4), 256, 0, stream>>>(
        e0, e1, e2, e3, bcur, pairs, N_EDGES);
    pass2_place<<<dim3(NBUCK, 4), 256, 0, stream>>>(
        pairs, bbase, rowptr, deg, col, N_EDGES, N_NODES);

    // ================= layer 0: qkv both hops (fp8 k/v), gather both hops =======
    qkv2_mfma<HID, true><<<QB, 256, 0, stream>>>(
        x, wq0b, bq0, wk0b, bk0, wv0b, bv0,
        q0h, q1h, k0c, k1c, v0c, v1c, N_NODES);
    gat2_128<<<NB, 256, 0, stream>>>(
        q0h, q1h,
        (const uint2*)k0c, (const uint2*)v0c, (const uint2*)k1c, (const uint2*)v1c,
        rowptr,            deg,            col,
        rowptr + N_NODES,  deg + N_NODES,  col + N_EDGES,
        acc, sc0, N_NODES);

    // ================= layer 1: qkv both hops (f16), gather + logsoftmax ========
    qkv2_mfma<CLS, false><<<QB, 256, 0, stream>>>(
        acc, wq1b, bq1, wk1b, bk1, wv1b, bv1,
        qA0, qA1, kA0, kA1, vA0, vA1, N_NODES);
    gat2_32<<<NB, 256, 0, stream>>>(
        qA0, qA1,
        (const uint4*)kA0, (const uint4*)vA0, (const uint4*)kA1, (const uint4*)vA1,
        rowptr + 2 * N_NODES, deg + 2 * N_NODES, col + (size_t)2 * N_EDGES,
        rowptr + 3 * N_NODES, deg + 3 * N_NODES, col + (size_t)3 * N_EDGES,
        out, sc1, N_NODES);
}